// Round 3
// baseline (17076.346 us; speedup 1.0000x reference)
//
#include <hip/hip_runtime.h>

// GPFA e-step posterior mean on MI355X.
// x = M^{-1} b.  NOTE the reference's einsum 'ftu,ij->tiuj' SUMS over f:
//   M[(t,i),(u,j)] = delta_ij * Kbar[t,u] + delta_tu * A[i,j],
//   Kbar = sum_f inv(K_f),  A = C' R^-1 C.
// K_f built+inverted in FP64 (blocked Gauss-Jordan, SPD no-pivot); Kbar = sum
// rounded to fp32 for batched PCG (block-Jacobi precond B_t = A + Kbar_tt*I,
// fixed 32 iters) with structured matvec:
//   (M p)[(t,f),c] = sum_u Kbar[t][u] p[(u,f),c] + sum_g A[f][g] p[(t,g),c]
// All vectors col-major: V[c][idx], idx = t*8+f, c = trial.

#define NF 8
#define TBINS 512
#define NNEU 512
#define NTRI 128
#define NTOT 4096          // NF*TBINS
#define N_ITERS 32

// ---- ws layout (float-offset units; doubles placed at even float offsets) ----
#define OFF_KD     0                 // double[8*512*512] = 16 MB (K, then Kinv in place)
#define OFF_KBAR   4194304           // float[512*512] = 1 MB (sum_f Kinv_f)
#define OFF_PINV64 6291456           // double[8*64*64]
#define OFF_RK64   6356992           // double[8*64*512]
#define OFF_FS64   6881280           // double[8*512*64]
#define OFF_CRVT   7405568           // float[4096]
#define OFF_CCT    7409664           // float[64]
#define OFF_CD     7409728           // float[64]
#define OFF_RINV   7409792           // float[512]
#define OFF_BINV   7410304           // float[512*64]
#define OFF_B      7443072           // b == r
#define OFF_X      7967360
#define OFF_P      8491648
#define OFF_Z      9015936
#define OFF_APK    9540224
#define OFF_SCAL   10064512          // rz0(128) rz1(128) pApK(128) pApA0(128) pApA1(128)

__device__ __forceinline__ void load8(float* v, const float* ptr){
  float4 a = ((const float4*)ptr)[0];
  float4 b = ((const float4*)ptr)[1];
  v[0]=a.x; v[1]=a.y; v[2]=a.z; v[3]=a.w;
  v[4]=b.x; v[5]=b.y; v[6]=b.z; v[7]=b.w;
}
__device__ __forceinline__ void store8(float* ptr, const float* v){
  ((float4*)ptr)[0] = make_float4(v[0],v[1],v[2],v[3]);
  ((float4*)ptr)[1] = make_float4(v[4],v[5],v[6],v[7]);
}

// ---------------- prep: rinv, c_rinv^T, A = C'R^-1 C, cd = C'R^-1 d ----------------
__global__ void prep_kernel(const float* __restrict__ Cm, const float* __restrict__ dm,
                            const float* __restrict__ r_diag,
                            float* __restrict__ crvT, float* __restrict__ ccT,
                            float* __restrict__ cd, float* __restrict__ rinv){
  __shared__ float s_crv[NNEU*NF];
  __shared__ float s_cm[NNEU*NF];
  __shared__ float s_dm[NNEU];
  int tid = threadIdx.x;            // 512 threads; thread == neuron n
  float ri = 1.0f / r_diag[tid];
  rinv[tid] = ri;
  s_dm[tid] = dm[tid];
  #pragma unroll
  for (int f = 0; f < NF; ++f){
    float cv = Cm[tid*NF + f];
    s_cm[tid*NF + f] = cv;
    float v = cv * ri;
    s_crv[tid*NF + f] = v;
    crvT[tid*NF + f] = v;
  }
  __syncthreads();
  if (tid < 64){
    int f = tid >> 3, g = tid & 7;
    float acc = 0.f;
    for (int n = 0; n < NNEU; ++n) acc += s_crv[n*NF+f] * s_cm[n*NF+g];
    ccT[tid] = acc;
  } else if (tid < 72){
    int f = tid - 64;
    float acc = 0.f;
    for (int n = 0; n < NNEU; ++n) acc += s_crv[n*NF+f] * s_dm[n];
    cd[f] = acc;
  }
}

// ---------------- build K_f in fp64 ----------------
__global__ void buildK64_kernel(const float* __restrict__ gamma, double* __restrict__ Kd){
  int f = blockIdx.y;
  int idx = blockIdx.x*256 + threadIdx.x;   // t*512+u
  int t = idx >> 9, u = idx & 511;
  double g = (double)gamma[f];
  double d = (double)(t - u);
  double v = (1.0 - 1.0e-3) * exp(-0.5 * g * d * d);
  if (t == u) v += 1.0e-3;
  Kd[(size_t)f*TBINS*TBINS + idx] = v;
}

// ---------------- fp64 blocked GJ inversion, BS=64 ----------------
__global__ void gj_pivot64(const double* __restrict__ Kd, double* __restrict__ Pinv, int k){
  __shared__ double Tt[64][65];
  __shared__ double colk[64];
  __shared__ double rowk[64];
  int f = blockIdx.x;
  int tid = threadIdx.x;            // 256
  int j = tid & 63, ig = tid >> 6;
  const double* A = Kd + (size_t)f*TBINS*TBINS;
  for (int i = ig*16; i < ig*16+16; ++i)
    Tt[i][j] = A[(size_t)(k*64+i)*TBINS + k*64 + j];
  __syncthreads();
  for (int kk = 0; kk < 64; ++kk){
    if (tid < 64) colk[tid] = Tt[tid][kk];
    else if (tid < 128) rowk[tid-64] = Tt[kk][tid-64];
    __syncthreads();
    double pinv = 1.0 / colk[kk];
    if (j == kk){
      #pragma unroll
      for (int m = 0; m < 16; ++m){
        int i = ig*16 + m;
        Tt[i][kk] = (i == kk) ? pinv : (-colk[i] * pinv);
      }
    } else {
      double newr = rowk[j] * pinv;
      #pragma unroll
      for (int m = 0; m < 16; ++m){
        int i = ig*16 + m;
        if (i == kk) Tt[kk][j] = newr;
        else Tt[i][j] -= colk[i] * newr;
      }
    }
    __syncthreads();
  }
  double* P = Pinv + f*4096;
  for (int i = ig*16; i < ig*16+16; ++i)
    P[i*64 + j] = Tt[i][j];
}

// Rk = P @ A[k-rows, :] (tiles bj=0..7); Fs = copy of A[:, k-cols] (bj=8)
__global__ void gj_rowcol64(const double* __restrict__ Kd, const double* __restrict__ Pinv,
                            double* __restrict__ Rk, double* __restrict__ Fs, int k){
  int f = blockIdx.y;
  int bj = blockIdx.x;
  int tid = threadIdx.x;            // 256
  int j = tid & 63, i0 = tid >> 6;
  const double* A = Kd + (size_t)f*TBINS*TBINS;
  if (bj == 8){
    double* Fsf = Fs + f*TBINS*64;
    for (int i = i0; i < TBINS; i += 4)
      Fsf[i*64 + j] = A[(size_t)i*TBINS + k*64 + j];
  } else {
    __shared__ double At[64][65];
    const double* P = Pinv + f*4096;
    for (int i = i0; i < 64; i += 4)
      At[i][j] = A[(size_t)(k*64+i)*TBINS + bj*64 + j];
    __syncthreads();
    double* Rkf = Rk + f*64*TBINS;
    for (int i = i0; i < 64; i += 4){
      double acc = 0.0;
      const double* Prow = P + i*64;       // wave-uniform (broadcast) reads
      for (int m = 0; m < 64; ++m) acc += Prow[m] * At[m][j];
      Rkf[i*TBINS + bj*64 + j] = acc;
    }
  }
}

__global__ void gj_update64(double* __restrict__ Kd, const double* __restrict__ Pinv,
                            const double* __restrict__ Rk, const double* __restrict__ Fs, int k){
  int f = blockIdx.y;
  int ti = blockIdx.x >> 3, tj = blockIdx.x & 7;
  int tid = threadIdx.x;            // 256
  int j = tid & 63, i0 = tid >> 6;
  double* A = Kd + (size_t)f*TBINS*TBINS;
  const double* P = Pinv + f*4096;
  if (ti == k && tj == k){
    for (int i = i0; i < 64; i += 4)
      A[(size_t)(k*64+i)*TBINS + k*64 + j] = P[i*64 + j];
  } else if (ti == k){
    const double* Rkf = Rk + f*64*TBINS;
    for (int i = i0; i < 64; i += 4)
      A[(size_t)(k*64+i)*TBINS + tj*64 + j] = Rkf[i*TBINS + tj*64 + j];
  } else if (tj == k){
    __shared__ double Pl[64][65];
    const double* Fsf = Fs + f*TBINS*64;
    for (int i = i0; i < 64; i += 4)
      Pl[i][j] = P[i*64 + j];
    __syncthreads();
    for (int i = i0; i < 64; i += 4){
      double acc = 0.0;
      const double* Frow = Fsf + (ti*64+i)*64;   // wave-uniform rows
      for (int m = 0; m < 64; ++m) acc += Frow[m] * Pl[m][j];
      A[(size_t)(ti*64+i)*TBINS + k*64 + j] = -acc;
    }
  } else {
    __shared__ double Rl[64][65];
    const double* Fsf = Fs + f*TBINS*64;
    const double* Rkf = Rk + f*64*TBINS;
    for (int i = i0; i < 64; i += 4)
      Rl[i][j] = Rkf[i*TBINS + tj*64 + j];
    __syncthreads();
    for (int i = i0; i < 64; i += 4){
      double acc = 0.0;
      const double* Frow = Fsf + (ti*64+i)*64;
      for (int m = 0; m < 64; ++m) acc += Frow[m] * Rl[m][j];
      A[(size_t)(ti*64+i)*TBINS + tj*64 + j] -= acc;
    }
  }
}

// ---------------- Kbar = sum_f Kinv_f  (fp64 sum -> fp32) ----------------
__global__ void sumk_kernel(const double* __restrict__ Kd, float* __restrict__ Kbar){
  size_t i = (size_t)blockIdx.x*256 + threadIdx.x;   // < 262144
  double s = 0.0;
  #pragma unroll
  for (int f = 0; f < NF; ++f) s += Kd[(size_t)f*TBINS*TBINS + i];
  Kbar[i] = (float)s;
}

// ---------------- block-Jacobi: Binv_t = inv(A + Kbar[t][t] * I8) (fp64 math) ----------------
__global__ void binv_kernel(const float* __restrict__ Kbar, const float* __restrict__ ccT,
                            float* __restrict__ Binv){
  int t = blockIdx.x*64 + threadIdx.x;
  double B[8][8];
  #pragma unroll
  for (int a = 0; a < 8; ++a)
    #pragma unroll
    for (int b = 0; b < 8; ++b) B[a][b] = (double)ccT[a*8+b];
  double kb = (double)Kbar[(size_t)t*TBINS + t];
  #pragma unroll
  for (int a = 0; a < 8; ++a) B[a][a] += kb;
  #pragma unroll
  for (int kk = 0; kk < 8; ++kk){
    double pinv = 1.0 / B[kk][kk];
    #pragma unroll
    for (int jj = 0; jj < 8; ++jj) if (jj != kk) B[kk][jj] *= pinv;
    #pragma unroll
    for (int ii = 0; ii < 8; ++ii){
      if (ii == kk) continue;
      double fct = B[ii][kk];
      #pragma unroll
      for (int jj = 0; jj < 8; ++jj) if (jj != kk) B[ii][jj] -= fct * B[kk][jj];
      B[ii][kk] = -fct * pinv;
    }
    B[kk][kk] = pinv;
  }
  #pragma unroll
  for (int a = 0; a < 8; ++a)
    #pragma unroll
    for (int b = 0; b < 8; ++b) Binv[t*64 + a*8 + b] = (float)B[a][b];
}

// ---------------- term1 (= b = r0): b[c][(t*8+f)] = sum_n crv[f][n] spike[c][n][t] - cd[f] ----------------
__global__ void term1_kernel(const float* __restrict__ spike, const float* __restrict__ crvT,
                             const float* __restrict__ cd, float* __restrict__ b){
  __shared__ float Sl[64][65];
  __shared__ float crl[NNEU*NF];   // [n][f]
  int t0 = blockIdx.x * 64;
  int r = blockIdx.y;
  int tid = threadIdx.x;           // 512
  int f = tid & 7, tt = tid >> 3;
  for (int n = tid; n < NNEU*NF; n += 512) crl[n] = crvT[n];
  float acc = 0.f;
  const float* Sp = spike + (size_t)r * NNEU * TBINS;
  int lj = tid & 63, li0 = tid >> 6;
  for (int nc = 0; nc < 8; ++nc){
    __syncthreads();
    for (int li = li0; li < 64; li += 8)
      Sl[li][lj] = Sp[(size_t)(nc*64 + li)*TBINS + t0 + lj];
    __syncthreads();
    #pragma unroll 8
    for (int nn = 0; nn < 64; ++nn)
      acc += crl[(nc*64+nn)*NF + f] * Sl[nn][tt];
  }
  b[(size_t)r * NTOT + (t0 + tt)*8 + f] = acc - cd[f];
}

// ---------------- PCG init: z0 = Binv b; p0 = z0; rz0 = b'z0; pApA0 = p0' D p0 ----------------
__global__ void cg_init_kernel(const float* __restrict__ b, const float* __restrict__ Binv,
                               const float* __restrict__ ccT,
                               float* __restrict__ z, float* __restrict__ p,
                               float* __restrict__ rz0, float* __restrict__ pApA0){
  __shared__ float Bl[32*65];
  __shared__ float Al[64];
  __shared__ float red[8*33];
  int tid = threadIdx.x;           // 256 = tq32 x cq8
  int tq = tid >> 3, cq = tid & 7;
  int t0 = blockIdx.x*32;
  int t = t0 + tq, c = blockIdx.y*8 + cq;
  if (tid < 64) Al[tid] = ccT[tid];
  for (int i2 = tid; i2 < 32*64; i2 += 256)
    Bl[(i2>>6)*65 + (i2&63)] = Binv[(t0 + (i2>>6))*64 + (i2&63)];
  __syncthreads();
  size_t base = (size_t)c*NTOT + t*8;
  float bv[8], zv[8];
  load8(bv, b + base);
  #pragma unroll
  for (int a = 0; a < 8; ++a){
    float s = 0.f;
    #pragma unroll
    for (int g = 0; g < 8; ++g) s += Bl[tq*65 + a*8+g] * bv[g];
    zv[a] = s;
  }
  store8(z + base, zv);
  store8(p + base, zv);
  float prz = 0.f, pap = 0.f;
  #pragma unroll
  for (int a = 0; a < 8; ++a){
    prz += bv[a]*zv[a];
    float s = 0.f;
    #pragma unroll
    for (int g = 0; g < 8; ++g) s += Al[a*8+g]*zv[g];
    pap += zv[a]*s;
  }
  red[cq*33+tq] = prz; __syncthreads();
  for (int s = 16; s > 0; s >>= 1){ if (tq < s) red[cq*33+tq] += red[cq*33+tq+s]; __syncthreads(); }
  if (tq == 0) atomicAdd(&rz0[c], red[cq*33]);
  __syncthreads();
  red[cq*33+tq] = pap; __syncthreads();
  for (int s = 16; s > 0; s >>= 1){ if (tq < s) red[cq*33+tq] += red[cq*33+tq+s]; __syncthreads(); }
  if (tq == 0) atomicAdd(&pApA0[c], red[cq*33]);
}

// ---------------- structured matvec: ApK[(t,f),c] = sum_u Kbar[t][u] p[(u,f),c] ; pApK += p'ApK ----------------
__global__ void matvec_kernel(const float* __restrict__ Kbar, const float* __restrict__ p,
                              float* __restrict__ ApK, float* __restrict__ pApK,
                              float* __restrict__ rz_zero){
  __shared__ float Kt[32*68];
  __shared__ float pch[64*65];
  __shared__ float red[64*9];
  int tid = threadIdx.x;           // 256
  int f = blockIdx.y;
  int t0 = blockIdx.x * 32;
  int c0 = blockIdx.z * 64;
  if (blockIdx.x == 0 && blockIdx.y == 0 && blockIdx.z == 0 && tid < 128) rz_zero[tid] = 0.f;
  int tq = tid >> 5, cq = tid & 31;
  float acc[4][2] = {{0.f,0.f},{0.f,0.f},{0.f,0.f},{0.f,0.f}};
  float pval[4][2];
  const float* Kf = Kbar;          // shared across all factors (reference sums over f)
  int tchunk = t0 >> 6;
  for (int uc = 0; uc < 8; ++uc){
    int u0 = uc*64;
    __syncthreads();
    {
      int c4 = (tid & 15) << 2, row = tid >> 4;
      *(float4*)&Kt[row*68 + c4]      = *(const float4*)(Kf + (size_t)(t0+row)*TBINS + u0 + c4);
      *(float4*)&Kt[(row+16)*68 + c4] = *(const float4*)(Kf + (size_t)(t0+row+16)*TBINS + u0 + c4);
    }
    {
      int uu = tid & 63, cc0 = tid >> 6;
      for (int cc = cc0; cc < 64; cc += 4)
        pch[uu*65 + cc] = p[(size_t)(c0+cc)*NTOT + (u0+uu)*8 + f];
    }
    __syncthreads();
    for (int uu = 0; uu < 64; ++uu){
      float pv0 = pch[uu*65 + cq], pv1 = pch[uu*65 + cq + 32];
      #pragma unroll
      for (int mt = 0; mt < 4; ++mt){
        float kv = Kt[(tq + 8*mt)*68 + uu];
        acc[mt][0] += kv * pv0;
        acc[mt][1] += kv * pv1;
      }
    }
    if (uc == tchunk){
      int duu = t0 - u0;
      #pragma unroll
      for (int mt = 0; mt < 4; ++mt){
        int uu_t = duu + tq + 8*mt;
        pval[mt][0] = pch[uu_t*65 + cq];
        pval[mt][1] = pch[uu_t*65 + cq + 32];
      }
    }
  }
  __syncthreads();
  #pragma unroll
  for (int mt = 0; mt < 4; ++mt){
    pch[(tq+8*mt)*65 + cq]      = acc[mt][0];
    pch[(tq+8*mt)*65 + cq + 32] = acc[mt][1];
  }
  __syncthreads();
  {
    int tl = tid & 31, cc0 = tid >> 5;
    for (int cc = cc0; cc < 64; cc += 8)
      ApK[(size_t)(c0+cc)*NTOT + (t0+tl)*8 + f] = pch[tl*65 + cc];
  }
  float prt0 = 0.f, prt1 = 0.f;
  #pragma unroll
  for (int mt = 0; mt < 4; ++mt){ prt0 += acc[mt][0]*pval[mt][0]; prt1 += acc[mt][1]*pval[mt][1]; }
  red[(cq)*9 + tq] = prt0;
  red[(cq+32)*9 + tq] = prt1;
  __syncthreads();
  if (tid < 64){
    float s = 0.f;
    #pragma unroll
    for (int q = 0; q < 8; ++q) s += red[tid*9+q];
    atomicAdd(&pApK[c0 + tid], s);
  }
}

// ---------------- x,r update; z = Binv r; rz_next = r'z ----------------
__global__ void update_xrz_kernel(float* __restrict__ x, float* __restrict__ r, float* __restrict__ z,
                                  const float* __restrict__ p, const float* __restrict__ ApK,
                                  const float* __restrict__ Binv, const float* __restrict__ ccT,
                                  const float* __restrict__ rz_cur, const float* __restrict__ pApK,
                                  const float* __restrict__ pApA_cur,
                                  float* __restrict__ rz_next, float* __restrict__ pApA_next){
  __shared__ float Bl[32*65];
  __shared__ float Al[64];
  __shared__ float red[8*33];
  int tid = threadIdx.x;
  if (blockIdx.x == 0 && blockIdx.y == 0 && tid < 128) pApA_next[tid] = 0.f;
  int tq = tid >> 3, cq = tid & 7;
  int t0 = blockIdx.x*32;
  int t = t0 + tq, c = blockIdx.y*8 + cq;
  if (tid < 64) Al[tid] = ccT[tid];
  for (int i2 = tid; i2 < 32*64; i2 += 256)
    Bl[(i2>>6)*65 + (i2&63)] = Binv[(t0 + (i2>>6))*64 + (i2&63)];
  __syncthreads();
  size_t base = (size_t)c*NTOT + t*8;
  float pv[8], av[8], xv[8], rv[8];
  load8(pv, p + base); load8(av, ApK + base); load8(xv, x + base); load8(rv, r + base);
  float alpha = rz_cur[c] / (pApK[c] + pApA_cur[c] + 1e-30f);
  float ap[8];
  #pragma unroll
  for (int a = 0; a < 8; ++a){
    float s = 0.f;
    #pragma unroll
    for (int g = 0; g < 8; ++g) s += Al[a*8+g]*pv[g];
    ap[a] = s;
  }
  #pragma unroll
  for (int a = 0; a < 8; ++a){
    xv[a] += alpha * pv[a];
    rv[a] -= alpha * (av[a] + ap[a]);
  }
  float zv[8];
  #pragma unroll
  for (int a = 0; a < 8; ++a){
    float s = 0.f;
    #pragma unroll
    for (int g = 0; g < 8; ++g) s += Bl[tq*65 + a*8+g] * rv[g];
    zv[a] = s;
  }
  store8(x + base, xv); store8(r + base, rv); store8(z + base, zv);
  float part = 0.f;
  #pragma unroll
  for (int a = 0; a < 8; ++a) part += rv[a]*zv[a];
  red[cq*33+tq] = part; __syncthreads();
  for (int s = 16; s > 0; s >>= 1){ if (tq < s) red[cq*33+tq] += red[cq*33+tq+s]; __syncthreads(); }
  if (tq == 0) atomicAdd(&rz_next[c], red[cq*33]);
}

// ---------------- p = z + beta p ; pApA_next += p' D p ----------------
__global__ void update_p_kernel(float* __restrict__ p, const float* __restrict__ z,
                                const float* __restrict__ rz_next, const float* __restrict__ rz_cur,
                                const float* __restrict__ ccT,
                                float* __restrict__ pApA_next, float* __restrict__ pApK){
  __shared__ float Al[64];
  __shared__ float red[8*33];
  int tid = threadIdx.x;
  if (blockIdx.x == 0 && blockIdx.y == 0 && tid < 128) pApK[tid] = 0.f;
  int tq = tid >> 3, cq = tid & 7;
  int t = blockIdx.x*32 + tq, c = blockIdx.y*8 + cq;
  if (tid < 64) Al[tid] = ccT[tid];
  __syncthreads();
  size_t base = (size_t)c*NTOT + t*8;
  float beta = rz_next[c] / (rz_cur[c] + 1e-30f);
  float pv[8], zv[8];
  load8(pv, p + base); load8(zv, z + base);
  #pragma unroll
  for (int a = 0; a < 8; ++a) pv[a] = zv[a] + beta * pv[a];
  store8(p + base, pv);
  float part = 0.f;
  #pragma unroll
  for (int a = 0; a < 8; ++a){
    float s = 0.f;
    #pragma unroll
    for (int g = 0; g < 8; ++g) s += Al[a*8+g]*pv[g];
    part += pv[a]*s;
  }
  red[cq*33+tq] = part; __syncthreads();
  for (int s = 16; s > 0; s >>= 1){ if (tq < s) red[cq*33+tq] += red[cq*33+tq+s]; __syncthreads(); }
  if (tq == 0) atomicAdd(&pApA_next[c], red[cq*33]);
}

// ---------------- output permute: out[r][f][t] = x[r][(t*8+f)] ----------------
__global__ void output_kernel(const float* __restrict__ x, float* __restrict__ out){
  int gid = blockIdx.x*256 + threadIdx.x;
  int r = gid >> 10;
  int rem = gid & 1023;
  int f = rem >> 7;
  int t4 = (rem & 127) << 2;
  const float* xb = x + (size_t)r*NTOT + f;
  float4 v;
  v.x = xb[(t4+0)*8];
  v.y = xb[(t4+1)*8];
  v.z = xb[(t4+2)*8];
  v.w = xb[(t4+3)*8];
  *(float4*)(out + (size_t)r*NF*TBINS + f*TBINS + t4) = v;
}

extern "C" void kernel_launch(void* const* d_in, const int* in_sizes, int n_in,
                              void* d_out, int out_size, void* d_ws, size_t ws_size,
                              hipStream_t stream) {
  const float* spike  = (const float*)d_in[0];
  const float* Cm     = (const float*)d_in[1];
  const float* dm     = (const float*)d_in[2];
  const float* r_diag = (const float*)d_in[3];
  const float* gamma  = (const float*)d_in[4];
  float* out = (float*)d_out;
  float* ws = (float*)d_ws;

  double* Kd    = (double*)(ws + OFF_KD);
  float*  Kbar  = ws + OFF_KBAR;
  double* Pinv  = (double*)(ws + OFF_PINV64);
  double* Rk    = (double*)(ws + OFF_RK64);
  double* Fs    = (double*)(ws + OFF_FS64);
  float* crvT = ws + OFF_CRVT;
  float* ccT  = ws + OFF_CCT;
  float* cd   = ws + OFF_CD;
  float* rinv = ws + OFF_RINV;
  float* Binv = ws + OFF_BINV;
  float* b    = ws + OFF_B;     // b == r (updated in place)
  float* x    = ws + OFF_X;
  float* p    = ws + OFF_P;
  float* z    = ws + OFF_Z;
  float* ApK  = ws + OFF_APK;
  float* rzA   = ws + OFF_SCAL;
  float* rzB   = ws + OFF_SCAL + 128;
  float* pApK  = ws + OFF_SCAL + 256;
  float* pApA0 = ws + OFF_SCAL + 384;
  float* pApA1 = ws + OFF_SCAL + 512;

  hipMemsetAsync(ws + OFF_SCAL, 0, 640*sizeof(float), stream);
  hipMemsetAsync(x, 0, (size_t)NTOT*NTRI*sizeof(float), stream);

  prep_kernel<<<1, 512, 0, stream>>>(Cm, dm, r_diag, crvT, ccT, cd, rinv);
  buildK64_kernel<<<dim3(1024, 8), 256, 0, stream>>>(gamma, Kd);
  for (int k = 0; k < 8; ++k){
    gj_pivot64<<<8, 256, 0, stream>>>(Kd, Pinv, k);
    gj_rowcol64<<<dim3(9, 8), 256, 0, stream>>>(Kd, Pinv, Rk, Fs, k);
    gj_update64<<<dim3(64, 8), 256, 0, stream>>>(Kd, Pinv, Rk, Fs, k);
  }
  sumk_kernel<<<1024, 256, 0, stream>>>(Kd, Kbar);
  binv_kernel<<<8, 64, 0, stream>>>(Kbar, ccT, Binv);
  term1_kernel<<<dim3(8, 128), 512, 0, stream>>>(spike, crvT, cd, b);
  cg_init_kernel<<<dim3(16, 16), 256, 0, stream>>>(b, Binv, ccT, z, p, rzA, pApA0);

  for (int i = 0; i < N_ITERS; ++i){
    float* rz_cur  = (i & 1) ? rzB : rzA;
    float* rz_next = (i & 1) ? rzA : rzB;
    float* pA_cur  = (i & 1) ? pApA1 : pApA0;
    float* pA_next = (i & 1) ? pApA0 : pApA1;
    matvec_kernel<<<dim3(16, 8, 2), 256, 0, stream>>>(Kbar, p, ApK, pApK, rz_next);
    update_xrz_kernel<<<dim3(16, 16), 256, 0, stream>>>(x, b, z, p, ApK, Binv, ccT,
                                                        rz_cur, pApK, pA_cur, rz_next, pA_next);
    if (i < N_ITERS - 1)
      update_p_kernel<<<dim3(16, 16), 256, 0, stream>>>(p, z, rz_next, rz_cur, ccT, pA_next, pApK);
  }
  output_kernel<<<512, 256, 0, stream>>>(x, out);
}

// Round 4
// 5225.914 us; speedup vs baseline: 3.2676x; 3.2676x over previous
//
#include <hip/hip_runtime.h>

// GPFA e-step posterior mean on MI355X — DIRECT Kronecker-sum solve.
// M = Kbar (x) I_F + I_T (x) A  (ordering idx = t*F+f),  Kbar = sum_f inv(K_f),
// A = C'R^-1 C = V Lam V'.  Conjugating by (I (x) V):
//   for each factor-eigenpair i:  (Kbar + lam_i I) xt_i = bt_i   (512x512, 128 RHS)
// K_f and G_i = Kbar + lam_i I inverted in FP64 (batched blocked Gauss-Jordan,
// SPD no-pivot).  H_i = inv(G_i) cast fp32; xt_i = H_i @ bt_i (one batched GEMM).
// V' fused into term1 (pre-rotated crv, cd); V fused into output permute.
// Vector layout: bt/xt[(t*8+i)*128 + c], c (trial) fastest.

#define NF 8
#define TBINS 512
#define NNEU 512
#define NTRI 128
#define NTOT 4096

// ---- ws layout (float offsets; fp64 arrays at even offsets) ----
#define OFF_KD     0                 // double[8*512*512] (K_f -> Kinv_f -> G_i -> Hinv_i)
#define OFF_KBAR64 4194304           // double[512*512]
#define OFF_PINV64 4718592           // double[8*64*64]
#define OFF_RK64   4784128           // double[8*64*512]
#define OFF_FS64   5308416           // double[8*512*64]
#define OFF_H      5832704           // float[8*512*512]
#define OFF_CRVT   7929856           // float[512*8]  [n][f]
#define OFF_CRVVT  7933952           // float[512*8]  [n][i] (V-rotated)
#define OFF_CCT    7938048           // float[64]     A
#define OFF_CD     7938112           // float[64]
#define OFF_CDV    7938176           // float[64]     V-rotated cd
#define OFF_RINV   7938240           // float[512]
#define OFF_LAM    7938752           // double[8]
#define OFF_VF     7938768           // float[64]     V[f][i] fp32
#define OFF_BT     7938832           // float[4096*128]
#define OFF_XT     8463120           // float[4096*128]

__device__ __forceinline__ void load8(float* v, const float* ptr){
  float4 a = ((const float4*)ptr)[0];
  float4 b = ((const float4*)ptr)[1];
  v[0]=a.x; v[1]=a.y; v[2]=a.z; v[3]=a.w;
  v[4]=b.x; v[5]=b.y; v[6]=b.z; v[7]=b.w;
}
__device__ __forceinline__ void store8(float* ptr, const float* v){
  ((float4*)ptr)[0] = make_float4(v[0],v[1],v[2],v[3]);
  ((float4*)ptr)[1] = make_float4(v[4],v[5],v[6],v[7]);
}

// ---------------- prep: rinv, c_rinv^T, A = C'R^-1 C, cd = C'R^-1 d ----------------
__global__ void prep_kernel(const float* __restrict__ Cm, const float* __restrict__ dm,
                            const float* __restrict__ r_diag,
                            float* __restrict__ crvT, float* __restrict__ ccT,
                            float* __restrict__ cd, float* __restrict__ rinv){
  __shared__ float s_crv[NNEU*NF];
  __shared__ float s_cm[NNEU*NF];
  __shared__ float s_dm[NNEU];
  int tid = threadIdx.x;            // 512; thread == neuron n
  float ri = 1.0f / r_diag[tid];
  rinv[tid] = ri;
  s_dm[tid] = dm[tid];
  #pragma unroll
  for (int f = 0; f < NF; ++f){
    float cv = Cm[tid*NF + f];
    s_cm[tid*NF + f] = cv;
    float v = cv * ri;
    s_crv[tid*NF + f] = v;
    crvT[tid*NF + f] = v;
  }
  __syncthreads();
  if (tid < 64){
    int f = tid >> 3, g = tid & 7;
    float acc = 0.f;
    for (int n = 0; n < NNEU; ++n) acc += s_crv[n*NF+f] * s_cm[n*NF+g];
    ccT[tid] = acc;
  } else if (tid < 72){
    int f = tid - 64;
    float acc = 0.f;
    for (int n = 0; n < NNEU; ++n) acc += s_crv[n*NF+f] * s_dm[n];
    cd[f] = acc;
  }
}

// ---------------- build K_f in fp64 ----------------
__global__ void buildK64_kernel(const float* __restrict__ gamma, double* __restrict__ Kd){
  int f = blockIdx.y;
  int idx = blockIdx.x*256 + threadIdx.x;   // t*512+u
  int t = idx >> 9, u = idx & 511;
  double g = (double)gamma[f];
  double d = (double)(t - u);
  double v = (1.0 - 1.0e-3) * exp(-0.5 * g * d * d);
  if (t == u) v += 1.0e-3;
  Kd[(size_t)f*TBINS*TBINS + idx] = v;
}

// ---------------- fp64 blocked GJ inversion (batch of 8), BS=64 ----------------
__global__ void gj_pivot64(const double* __restrict__ Kd, double* __restrict__ Pinv, int k){
  __shared__ double Tt[64][65];
  __shared__ double colk[64];
  __shared__ double rowk[64];
  int f = blockIdx.x;
  int tid = threadIdx.x;            // 256
  int j = tid & 63, ig = tid >> 6;
  const double* A = Kd + (size_t)f*TBINS*TBINS;
  for (int i = ig*16; i < ig*16+16; ++i)
    Tt[i][j] = A[(size_t)(k*64+i)*TBINS + k*64 + j];
  __syncthreads();
  for (int kk = 0; kk < 64; ++kk){
    if (tid < 64) colk[tid] = Tt[tid][kk];
    else if (tid < 128) rowk[tid-64] = Tt[kk][tid-64];
    __syncthreads();
    double pinv = 1.0 / colk[kk];
    if (j == kk){
      #pragma unroll
      for (int m = 0; m < 16; ++m){
        int i = ig*16 + m;
        Tt[i][kk] = (i == kk) ? pinv : (-colk[i] * pinv);
      }
    } else {
      double newr = rowk[j] * pinv;
      #pragma unroll
      for (int m = 0; m < 16; ++m){
        int i = ig*16 + m;
        if (i == kk) Tt[kk][j] = newr;
        else Tt[i][j] -= colk[i] * newr;
      }
    }
    __syncthreads();
  }
  double* P = Pinv + f*4096;
  for (int i = ig*16; i < ig*16+16; ++i)
    P[i*64 + j] = Tt[i][j];
}

__global__ void gj_rowcol64(const double* __restrict__ Kd, const double* __restrict__ Pinv,
                            double* __restrict__ Rk, double* __restrict__ Fs, int k){
  int f = blockIdx.y;
  int bj = blockIdx.x;
  int tid = threadIdx.x;            // 256
  int j = tid & 63, i0 = tid >> 6;
  const double* A = Kd + (size_t)f*TBINS*TBINS;
  if (bj == 8){
    double* Fsf = Fs + f*TBINS*64;
    for (int i = i0; i < TBINS; i += 4)
      Fsf[i*64 + j] = A[(size_t)i*TBINS + k*64 + j];
  } else {
    __shared__ double At[64][65];
    const double* P = Pinv + f*4096;
    for (int i = i0; i < 64; i += 4)
      At[i][j] = A[(size_t)(k*64+i)*TBINS + bj*64 + j];
    __syncthreads();
    double* Rkf = Rk + f*64*TBINS;
    for (int i = i0; i < 64; i += 4){
      double acc = 0.0;
      const double* Prow = P + i*64;       // wave-uniform broadcast
      for (int m = 0; m < 64; ++m) acc += Prow[m] * At[m][j];
      Rkf[i*TBINS + bj*64 + j] = acc;
    }
  }
}

__global__ void gj_update64(double* __restrict__ Kd, const double* __restrict__ Pinv,
                            const double* __restrict__ Rk, const double* __restrict__ Fs, int k){
  int f = blockIdx.y;
  int ti = blockIdx.x >> 3, tj = blockIdx.x & 7;
  int tid = threadIdx.x;            // 256
  int j = tid & 63, i0 = tid >> 6;
  double* A = Kd + (size_t)f*TBINS*TBINS;
  const double* P = Pinv + f*4096;
  if (ti == k && tj == k){
    for (int i = i0; i < 64; i += 4)
      A[(size_t)(k*64+i)*TBINS + k*64 + j] = P[i*64 + j];
  } else if (ti == k){
    const double* Rkf = Rk + f*64*TBINS;
    for (int i = i0; i < 64; i += 4)
      A[(size_t)(k*64+i)*TBINS + tj*64 + j] = Rkf[i*TBINS + tj*64 + j];
  } else if (tj == k){
    __shared__ double Pl[64][65];
    const double* Fsf = Fs + f*TBINS*64;
    for (int i = i0; i < 64; i += 4)
      Pl[i][j] = P[i*64 + j];
    __syncthreads();
    for (int i = i0; i < 64; i += 4){
      double acc = 0.0;
      const double* Frow = Fsf + (ti*64+i)*64;
      for (int m = 0; m < 64; ++m) acc += Frow[m] * Pl[m][j];
      A[(size_t)(ti*64+i)*TBINS + k*64 + j] = -acc;
    }
  } else {
    __shared__ double Rl[64][65];
    const double* Fsf = Fs + f*TBINS*64;
    const double* Rkf = Rk + f*64*TBINS;
    for (int i = i0; i < 64; i += 4)
      Rl[i][j] = Rkf[i*TBINS + tj*64 + j];
    __syncthreads();
    for (int i = i0; i < 64; i += 4){
      double acc = 0.0;
      const double* Frow = Fsf + (ti*64+i)*64;
      for (int m = 0; m < 64; ++m) acc += Frow[m] * Rl[m][j];
      A[(size_t)(ti*64+i)*TBINS + tj*64 + j] -= acc;
    }
  }
}

// ---------------- Kbar64 = sum_f Kinv_f (fp64) ----------------
__global__ void sumk64_kernel(const double* __restrict__ Kd, double* __restrict__ Kbar64){
  size_t idx = (size_t)blockIdx.x*256 + threadIdx.x;   // < 262144
  double s = 0.0;
  #pragma unroll
  for (int f = 0; f < NF; ++f) s += Kd[(size_t)f*TBINS*TBINS + idx];
  Kbar64[idx] = s;
}

// ---------------- 8x8 symmetric eigendecomposition (cyclic Jacobi, fp64) ----------------
__global__ void eig8_kernel(const float* __restrict__ ccT,
                            float* __restrict__ Vf, double* __restrict__ lam){
  if (threadIdx.x != 0) return;
  double A[8][8], V[8][8];
  #pragma unroll
  for (int a = 0; a < 8; ++a)
    #pragma unroll
    for (int b = 0; b < 8; ++b){
      A[a][b] = (double)ccT[a*8+b];
      V[a][b] = (a == b) ? 1.0 : 0.0;
    }
  #pragma unroll
  for (int sw = 0; sw < 8; ++sw){
    #pragma unroll
    for (int p = 0; p < 7; ++p){
      #pragma unroll
      for (int q = p+1; q < 8; ++q){
        double apq = A[p][q];
        if (fabs(apq) > 1e-300){
          double th = 0.5 * atan2(2.0*apq, A[q][q]-A[p][p]);
          double c = cos(th), s = sin(th);
          #pragma unroll
          for (int kk = 0; kk < 8; ++kk){
            double akp = A[kk][p], akq = A[kk][q];
            A[kk][p] = c*akp - s*akq;
            A[kk][q] = s*akp + c*akq;
          }
          #pragma unroll
          for (int kk = 0; kk < 8; ++kk){
            double apk = A[p][kk], aqk = A[q][kk];
            A[p][kk] = c*apk - s*aqk;
            A[q][kk] = s*apk + c*aqk;
          }
          #pragma unroll
          for (int kk = 0; kk < 8; ++kk){
            double vkp = V[kk][p], vkq = V[kk][q];
            V[kk][p] = c*vkp - s*vkq;
            V[kk][q] = s*vkp + c*vkq;
          }
        }
      }
    }
  }
  #pragma unroll
  for (int i = 0; i < 8; ++i) lam[i] = A[i][i];
  #pragma unroll
  for (int a = 0; a < 8; ++a)
    #pragma unroll
    for (int b = 0; b < 8; ++b) Vf[a*8+b] = (float)V[a][b];
}

// ---------------- rotate crv, cd by V^T:  crvVT[n][i] = sum_f V[f][i] crvT[n][f] ----------------
__global__ void rotv_kernel(const float* __restrict__ crvT, const float* __restrict__ cd,
                            const float* __restrict__ Vf,
                            float* __restrict__ crvVT, float* __restrict__ cdV){
  __shared__ float Vl[64];
  int tid = threadIdx.x;   // 512
  if (tid < 64) Vl[tid] = Vf[tid];
  __syncthreads();
  float cv[8], ov[8];
  load8(cv, crvT + tid*8);
  #pragma unroll
  for (int i = 0; i < 8; ++i){
    float s = 0.f;
    #pragma unroll
    for (int f = 0; f < 8; ++f) s += Vl[f*8+i] * cv[f];
    ov[i] = s;
  }
  store8(crvVT + tid*8, ov);
  if (tid < 8){
    float s = 0.f;
    #pragma unroll
    for (int f = 0; f < 8; ++f) s += Vl[f*8+tid] * cd[f];
    cdV[tid] = s;
  }
}

// ---------------- G_i = Kbar + lam_i I (fp64, in place over Kd slots) ----------------
__global__ void buildG_kernel(const double* __restrict__ Kbar64, const double* __restrict__ lam,
                              double* __restrict__ Kd){
  int i = blockIdx.y;
  int idx = blockIdx.x*256 + threadIdx.x;   // t*512+u
  double v = Kbar64[idx];
  if ((idx >> 9) == (idx & 511)) v += lam[i];
  Kd[(size_t)i*TBINS*TBINS + idx] = v;
}

// ---------------- H_i = (float) inv(G_i) ----------------
__global__ void castH_kernel(const double* __restrict__ Kd, float* __restrict__ H){
  int i = blockIdx.y;
  size_t idx = (size_t)blockIdx.x*256 + threadIdx.x;
  H[(size_t)i*TBINS*TBINS + idx] = (float)Kd[(size_t)i*TBINS*TBINS + idx];
}

// ---------------- term1 (V^T-rotated): bt[(t*8+i)*128+c] = sum_n crvV[i][n] spike[c][n][t] - cdV[i] ----------------
__global__ void term1_kernel(const float* __restrict__ spike, const float* __restrict__ crvVT,
                             const float* __restrict__ cdV, float* __restrict__ bt){
  __shared__ float crl[NNEU*NF];   // [n][i]
  __shared__ float ot[128][17];
  int t0 = blockIdx.x * 16;
  int c0 = blockIdx.y * 16;
  int tid = threadIdx.x;           // 256
  int tl = tid & 15, cl = tid >> 4;
  for (int n2 = tid; n2 < NNEU*NF; n2 += 256) crl[n2] = crvVT[n2];
  __syncthreads();
  float acc[8] = {0.f,0.f,0.f,0.f,0.f,0.f,0.f,0.f};
  const float* Sp = spike + (size_t)(c0+cl)*NNEU*TBINS + t0 + tl;
  for (int n = 0; n < NNEU; n += 4){
    float s0 = Sp[(size_t)(n+0)*TBINS];
    float s1 = Sp[(size_t)(n+1)*TBINS];
    float s2 = Sp[(size_t)(n+2)*TBINS];
    float s3 = Sp[(size_t)(n+3)*TBINS];
    #pragma unroll
    for (int i = 0; i < 8; ++i)
      acc[i] += crl[(n+0)*8+i]*s0 + crl[(n+1)*8+i]*s1 + crl[(n+2)*8+i]*s2 + crl[(n+3)*8+i]*s3;
  }
  #pragma unroll
  for (int i = 0; i < 8; ++i) ot[tl*8+i][cl] = acc[i] - cdV[i];
  __syncthreads();
  int row = tid >> 1, off = (tid & 1) * 8;    // row = tlocal*8+i
  int tt = t0 + (row >> 3), ii = row & 7;
  float* dst = bt + (size_t)(tt*8+ii)*NTRI + c0 + off;
  #pragma unroll
  for (int k = 0; k < 8; ++k) dst[k] = ot[row][off+k];
}

// ---------------- batched GEMM: xt_i = H_i (512x512) @ bt_i (512x128) ----------------
__global__ void gemm_kernel(const float* __restrict__ H, const float* __restrict__ bt,
                            float* __restrict__ xt){
  __shared__ float Ht[32][68];
  __shared__ float Bt[64][128];
  int i  = blockIdx.y;
  int t0 = blockIdx.x * 32;
  int tid = threadIdx.x;           // 256
  int gt = tid >> 5;               // 0..7
  int gc = tid & 31;               // 0..31
  float acc[4][4] = {{0.f,0.f,0.f,0.f},{0.f,0.f,0.f,0.f},{0.f,0.f,0.f,0.f},{0.f,0.f,0.f,0.f}};
  const float* Hi = H + (size_t)i*TBINS*TBINS;
  for (int uc = 0; uc < 8; ++uc){
    int u0 = uc*64;
    __syncthreads();
    for (int v = tid; v < 512; v += 256){
      int r = v >> 4, c4 = (v & 15) << 2;
      *(float4*)&Ht[r][c4] = *(const float4*)(Hi + (size_t)(t0+r)*TBINS + u0 + c4);
    }
    for (int v = tid; v < 2048; v += 256){
      int r = v >> 5, c4 = (v & 31) << 2;
      *(float4*)&Bt[r][c4] = *(const float4*)(bt + (size_t)((u0+r)*8 + i)*NTRI + c4);
    }
    __syncthreads();
    for (int u = 0; u < 64; ++u){
      float h0 = Ht[gt*4+0][u], h1 = Ht[gt*4+1][u], h2 = Ht[gt*4+2][u], h3 = Ht[gt*4+3][u];
      float b0 = Bt[u][gc], b1 = Bt[u][gc+32], b2 = Bt[u][gc+64], b3 = Bt[u][gc+96];
      acc[0][0] += h0*b0; acc[0][1] += h0*b1; acc[0][2] += h0*b2; acc[0][3] += h0*b3;
      acc[1][0] += h1*b0; acc[1][1] += h1*b1; acc[1][2] += h1*b2; acc[1][3] += h1*b3;
      acc[2][0] += h2*b0; acc[2][1] += h2*b1; acc[2][2] += h2*b2; acc[2][3] += h2*b3;
      acc[3][0] += h3*b0; acc[3][1] += h3*b1; acc[3][2] += h3*b2; acc[3][3] += h3*b3;
    }
  }
  #pragma unroll
  for (int m = 0; m < 4; ++m)
    #pragma unroll
    for (int j = 0; j < 4; ++j)
      xt[(size_t)((t0 + gt*4 + m)*8 + i)*NTRI + gc + 32*j] = acc[m][j];
}

// ---------------- output: out[c][f][t] = sum_i V[f][i] xt[(t*8+i)*128+c] ----------------
__global__ void output_kernel(const float* __restrict__ xt, const float* __restrict__ Vf,
                              float* __restrict__ out){
  __shared__ float T[128][68];
  __shared__ float Vl[64];
  int t0 = blockIdx.x * 64, c0 = blockIdx.y * 16;
  int tid = threadIdx.x;   // 256
  if (tid < 64) Vl[tid] = Vf[tid];
  __syncthreads();
  for (int idx = tid; idx < 1024; idx += 256){
    int tl = idx >> 4, cl = idx & 15;
    float xv[8];
    #pragma unroll
    for (int i = 0; i < 8; ++i)
      xv[i] = xt[(size_t)((t0+tl)*8+i)*NTRI + c0 + cl];
    #pragma unroll
    for (int f = 0; f < 8; ++f){
      float s = 0.f;
      #pragma unroll
      for (int i = 0; i < 8; ++i) s += Vl[f*8+i] * xv[i];
      T[cl*8+f][tl] = s;
    }
  }
  __syncthreads();
  int row = tid >> 1, half = tid & 1;   // row = cl*8+f
  int cc = c0 + (row >> 3), ff = row & 7;
  float* dst = out + (size_t)cc*NF*TBINS + ff*TBINS + t0 + half*32;
  #pragma unroll
  for (int k = 0; k < 8; ++k)
    ((float4*)dst)[k] = *(float4*)&T[row][half*32 + k*4];
}

extern "C" void kernel_launch(void* const* d_in, const int* in_sizes, int n_in,
                              void* d_out, int out_size, void* d_ws, size_t ws_size,
                              hipStream_t stream) {
  const float* spike  = (const float*)d_in[0];
  const float* Cm     = (const float*)d_in[1];
  const float* dm     = (const float*)d_in[2];
  const float* r_diag = (const float*)d_in[3];
  const float* gamma  = (const float*)d_in[4];
  float* out = (float*)d_out;
  float* ws = (float*)d_ws;

  double* Kd     = (double*)(ws + OFF_KD);
  double* Kbar64 = (double*)(ws + OFF_KBAR64);
  double* Pinv   = (double*)(ws + OFF_PINV64);
  double* Rk     = (double*)(ws + OFF_RK64);
  double* Fs     = (double*)(ws + OFF_FS64);
  float*  H      = ws + OFF_H;
  float*  crvT   = ws + OFF_CRVT;
  float*  crvVT  = ws + OFF_CRVVT;
  float*  ccT    = ws + OFF_CCT;
  float*  cd     = ws + OFF_CD;
  float*  cdV    = ws + OFF_CDV;
  float*  rinv   = ws + OFF_RINV;
  double* lam    = (double*)(ws + OFF_LAM);
  float*  Vf     = ws + OFF_VF;
  float*  bt     = ws + OFF_BT;
  float*  xt     = ws + OFF_XT;

  prep_kernel<<<1, 512, 0, stream>>>(Cm, dm, r_diag, crvT, ccT, cd, rinv);
  buildK64_kernel<<<dim3(1024, 8), 256, 0, stream>>>(gamma, Kd);
  for (int k = 0; k < 8; ++k){
    gj_pivot64<<<8, 256, 0, stream>>>(Kd, Pinv, k);
    gj_rowcol64<<<dim3(9, 8), 256, 0, stream>>>(Kd, Pinv, Rk, Fs, k);
    gj_update64<<<dim3(64, 8), 256, 0, stream>>>(Kd, Pinv, Rk, Fs, k);
  }
  sumk64_kernel<<<1024, 256, 0, stream>>>(Kd, Kbar64);
  eig8_kernel<<<1, 64, 0, stream>>>(ccT, Vf, lam);
  rotv_kernel<<<1, 512, 0, stream>>>(crvT, cd, Vf, crvVT, cdV);
  buildG_kernel<<<dim3(1024, 8), 256, 0, stream>>>(Kbar64, lam, Kd);
  for (int k = 0; k < 8; ++k){
    gj_pivot64<<<8, 256, 0, stream>>>(Kd, Pinv, k);
    gj_rowcol64<<<dim3(9, 8), 256, 0, stream>>>(Kd, Pinv, Rk, Fs, k);
    gj_update64<<<dim3(64, 8), 256, 0, stream>>>(Kd, Pinv, Rk, Fs, k);
  }
  castH_kernel<<<dim3(1024, 8), 256, 0, stream>>>(Kd, H);
  term1_kernel<<<dim3(32, 8), 256, 0, stream>>>(spike, crvVT, cdV, bt);
  gemm_kernel<<<dim3(16, 8), 256, 0, stream>>>(H, bt, xt);
  output_kernel<<<dim3(8, 8), 256, 0, stream>>>(xt, Vf, out);
}

// Round 5
// 3096.719 us; speedup vs baseline: 5.5143x; 1.6876x over previous
//
#include <hip/hip_runtime.h>

// GPFA e-step posterior mean on MI355X — direct Kronecker-sum solve, fp32 chains.
// M = Kbar (x) I_F + I_T (x) A,  Kbar = sum_f inv(K_f),  A = C'R^-1 C = V Lam V'.
// Per factor-eigenpair i: (Kbar + lam_i I) xt_i = bt_i  (512x512, 128 RHS).
// Both inversion chains: fp32 blocked Gauss-Jordan, BS=64, ONE fused kernel per
// step (ping-pong buffers; each block redundantly inverts the pivot in LDS).
// V' fused into term1; V fused into output permute.

#define NF 8
#define TBINS 512
#define NNEU 512
#define NTRI 128
#define PAD 68

// ---- ws layout (float offsets) ----
#define OFF_A0     0                 // float[8*512*512] ping
#define OFF_A1     2097152           // float[8*512*512] pong
#define OFF_CRVT   4194304           // float[512*8]
#define OFF_CRVVT  4198400           // float[512*8]
#define OFF_CCT    4202496           // float[64]
#define OFF_CD     4202560           // float[64]
#define OFF_CDV    4202624           // float[64]
#define OFF_RINV   4202688           // float[512]
#define OFF_LAM    4203200           // double[8] (even float offset)
#define OFF_VF     4203216           // float[64]
#define OFF_BT     4203280           // float[4096*128]
#define OFF_XT     4727568           // float[4096*128]

__device__ __forceinline__ void load8(float* v, const float* ptr){
  float4 a = ((const float4*)ptr)[0];
  float4 b = ((const float4*)ptr)[1];
  v[0]=a.x; v[1]=a.y; v[2]=a.z; v[3]=a.w;
  v[4]=b.x; v[5]=b.y; v[6]=b.z; v[7]=b.w;
}
__device__ __forceinline__ void store8(float* ptr, const float* v){
  ((float4*)ptr)[0] = make_float4(v[0],v[1],v[2],v[3]);
  ((float4*)ptr)[1] = make_float4(v[4],v[5],v[6],v[7]);
}

// ---------------- prep ----------------
__global__ void prep_kernel(const float* __restrict__ Cm, const float* __restrict__ dm,
                            const float* __restrict__ r_diag,
                            float* __restrict__ crvT, float* __restrict__ ccT,
                            float* __restrict__ cd, float* __restrict__ rinv){
  __shared__ float s_crv[NNEU*NF];
  __shared__ float s_cm[NNEU*NF];
  __shared__ float s_dm[NNEU];
  int tid = threadIdx.x;            // 512; thread == neuron n
  float ri = 1.0f / r_diag[tid];
  rinv[tid] = ri;
  s_dm[tid] = dm[tid];
  #pragma unroll
  for (int f = 0; f < NF; ++f){
    float cv = Cm[tid*NF + f];
    s_cm[tid*NF + f] = cv;
    float v = cv * ri;
    s_crv[tid*NF + f] = v;
    crvT[tid*NF + f] = v;
  }
  __syncthreads();
  if (tid < 64){
    int f = tid >> 3, g = tid & 7;
    float acc = 0.f;
    for (int n = 0; n < NNEU; ++n) acc += s_crv[n*NF+f] * s_cm[n*NF+g];
    ccT[tid] = acc;
  } else if (tid < 72){
    int f = tid - 64;
    float acc = 0.f;
    for (int n = 0; n < NNEU; ++n) acc += s_crv[n*NF+f] * s_dm[n];
    cd[f] = acc;
  }
}

// ---------------- 8x8 eig: cyclic Jacobi, ALGEBRAIC rotations (no transcendentals) ----------------
__global__ void eig8_kernel(const float* __restrict__ ccT,
                            float* __restrict__ Vf, double* __restrict__ lam){
  if (threadIdx.x != 0) return;
  double A[8][8], V[8][8];
  #pragma unroll
  for (int a = 0; a < 8; ++a)
    #pragma unroll
    for (int b = 0; b < 8; ++b){
      A[a][b] = (double)ccT[a*8+b];
      V[a][b] = (a == b) ? 1.0 : 0.0;
    }
  for (int sw = 0; sw < 12; ++sw){
    for (int p = 0; p < 7; ++p){
      for (int q = p+1; q < 8; ++q){
        double apq = A[p][q];
        if (fabs(apq) < 1e-300) continue;
        double beta = (A[q][q] - A[p][p]) / (2.0 * apq);
        double tt = ((beta >= 0.0) ? 1.0 : -1.0) / (fabs(beta) + sqrt(1.0 + beta*beta));
        double c = 1.0 / sqrt(1.0 + tt*tt);
        double s = tt * c;
        #pragma unroll
        for (int kk = 0; kk < 8; ++kk){
          double akp = A[kk][p], akq = A[kk][q];
          A[kk][p] = c*akp - s*akq;
          A[kk][q] = s*akp + c*akq;
        }
        #pragma unroll
        for (int kk = 0; kk < 8; ++kk){
          double apk = A[p][kk], aqk = A[q][kk];
          A[p][kk] = c*apk - s*aqk;
          A[q][kk] = s*apk + c*aqk;
        }
        #pragma unroll
        for (int kk = 0; kk < 8; ++kk){
          double vkp = V[kk][p], vkq = V[kk][q];
          V[kk][p] = c*vkp - s*vkq;
          V[kk][q] = s*vkp + c*vkq;
        }
      }
    }
  }
  #pragma unroll
  for (int i = 0; i < 8; ++i) lam[i] = A[i][i];
  #pragma unroll
  for (int a = 0; a < 8; ++a)
    #pragma unroll
    for (int b = 0; b < 8; ++b) Vf[a*8+b] = (float)V[a][b];
}

// ---------------- rotate crv, cd by V^T ----------------
__global__ void rotv_kernel(const float* __restrict__ crvT, const float* __restrict__ cd,
                            const float* __restrict__ Vf,
                            float* __restrict__ crvVT, float* __restrict__ cdV){
  __shared__ float Vl[64];
  int tid = threadIdx.x;   // 512
  if (tid < 64) Vl[tid] = Vf[tid];
  __syncthreads();
  float cv[8], ov[8];
  load8(cv, crvT + tid*8);
  #pragma unroll
  for (int i = 0; i < 8; ++i){
    float s = 0.f;
    #pragma unroll
    for (int f = 0; f < 8; ++f) s += Vl[f*8+i] * cv[f];
    ov[i] = s;
  }
  store8(crvVT + tid*8, ov);
  if (tid < 8){
    float s = 0.f;
    #pragma unroll
    for (int f = 0; f < 8; ++f) s += Vl[f*8+tid] * cd[f];
    cdV[tid] = s;
  }
}

// ---------------- build K_f (fp32) ----------------
__global__ void buildK_kernel(const float* __restrict__ gamma, float* __restrict__ A0){
  int f = blockIdx.y;
  int idx = blockIdx.x*256 + threadIdx.x;   // t*512+u
  int t = idx >> 9, u = idx & 511;
  float g = gamma[f];
  float d = (float)(t - u);
  float v = 0.999f * expf(-0.5f * g * d * d);
  if (t == u) v += 1.0e-3f;
  A0[(size_t)f*TBINS*TBINS + idx] = v;
}

// ---------------- fused GJ step: src -> dst, block k eliminated ----------------
// grid (64 tiles, 8 mats), 256 threads. Each block redundantly inverts the
// 64x64 pivot in LDS, then computes its (ti,tj) output tile.
#define ACC4(tm, fm) \
  tm[0] += fm.x*s0.x + fm.y*s1.x + fm.z*s2.x + fm.w*s3.x; \
  tm[1] += fm.x*s0.y + fm.y*s1.y + fm.z*s2.y + fm.w*s3.y; \
  tm[2] += fm.x*s0.z + fm.y*s1.z + fm.z*s2.z + fm.w*s3.z; \
  tm[3] += fm.x*s0.w + fm.y*s1.w + fm.z*s2.w + fm.w*s3.w;

__global__ __launch_bounds__(256) void gj_step(const float* __restrict__ src,
                                               float* __restrict__ dst, int k){
  __shared__ float P[64*PAD];
  __shared__ float Q[64*PAD];
  __shared__ float F[64*PAD];
  __shared__ float colk[64];
  __shared__ float rowk[64];
  int f  = blockIdx.y;
  int ti = blockIdx.x >> 3, tj = blockIdx.x & 7;
  int tid = threadIdx.x;
  const float* A = src + (size_t)f*TBINS*TBINS;
  float* D = dst + (size_t)f*TBINS*TBINS;
  bool needQ = (tj != k);
  bool needF = (ti != k);

  for (int v = tid; v < 1024; v += 256){
    int r = v >> 4, c4 = (v & 15) << 2;
    *(float4*)&P[r*PAD + c4] = *(const float4*)(A + (size_t)(k*64+r)*TBINS + k*64 + c4);
  }
  if (needQ){
    for (int v = tid; v < 1024; v += 256){
      int r = v >> 4, c4 = (v & 15) << 2;
      *(float4*)&Q[r*PAD + c4] = *(const float4*)(A + (size_t)(k*64+r)*TBINS + tj*64 + c4);
    }
  }
  if (needF){
    for (int v = tid; v < 1024; v += 256){
      int r = v >> 4, c4 = (v & 15) << 2;
      *(float4*)&F[r*PAD + c4] = *(const float4*)(A + (size_t)(ti*64+r)*TBINS + k*64 + c4);
    }
  }
  __syncthreads();

  // in-place GJ inversion of P (SPD, no pivoting)
  {
    int j = tid & 63, ig = tid >> 6;
    for (int kk = 0; kk < 64; ++kk){
      if (tid < 64) colk[tid] = P[tid*PAD + kk];
      else if (tid < 128) rowk[tid-64] = P[kk*PAD + (tid-64)];
      __syncthreads();
      float pinv = 1.0f / colk[kk];
      if (j == kk){
        #pragma unroll
        for (int m = 0; m < 16; ++m){
          int i = ig*16 + m;
          P[i*PAD + kk] = (i == kk) ? pinv : (-colk[i] * pinv);
        }
      } else {
        float newr = rowk[j] * pinv;
        #pragma unroll
        for (int m = 0; m < 16; ++m){
          int i = ig*16 + m;
          if (i == kk) P[kk*PAD + j] = newr;
          else P[i*PAD + j] -= colk[i] * newr;
        }
      }
      __syncthreads();
    }
  }

  int jg = (tid & 15) << 2;   // output cols jg..jg+3
  int ib = (tid >> 4) << 2;   // output rows ib..ib+3

  if (ti == k && tj == k){
    for (int v = tid; v < 1024; v += 256){
      int r = v >> 4, c4 = (v & 15) << 2;
      *(float4*)(D + (size_t)(k*64+r)*TBINS + k*64 + c4) = *(float4*)&P[r*PAD + c4];
    }
    return;
  }

  if (needQ){
    // T = P @ Q  (inv(pivot) is symmetric: read P[u][ib..] as P[ib..][u])
    float t[4][4] = {{0.f,0.f,0.f,0.f},{0.f,0.f,0.f,0.f},{0.f,0.f,0.f,0.f},{0.f,0.f,0.f,0.f}};
    for (int u = 0; u < 64; ++u){
      float4 pv = *(float4*)&P[u*PAD + ib];
      float4 qv = *(float4*)&Q[u*PAD + jg];
      t[0][0]+=pv.x*qv.x; t[0][1]+=pv.x*qv.y; t[0][2]+=pv.x*qv.z; t[0][3]+=pv.x*qv.w;
      t[1][0]+=pv.y*qv.x; t[1][1]+=pv.y*qv.y; t[1][2]+=pv.y*qv.z; t[1][3]+=pv.y*qv.w;
      t[2][0]+=pv.z*qv.x; t[2][1]+=pv.z*qv.y; t[2][2]+=pv.z*qv.z; t[2][3]+=pv.z*qv.w;
      t[3][0]+=pv.w*qv.x; t[3][1]+=pv.w*qv.y; t[3][2]+=pv.w*qv.z; t[3][3]+=pv.w*qv.w;
    }
    __syncthreads();               // all reads of Q done
    #pragma unroll
    for (int m = 0; m < 4; ++m)
      *(float4*)&Q[(ib+m)*PAD + jg] = make_float4(t[m][0],t[m][1],t[m][2],t[m][3]);
    if (ti == k){                  // output is T itself
      #pragma unroll
      for (int m = 0; m < 4; ++m)
        *(float4*)(D + (size_t)(k*64+ib+m)*TBINS + tj*64 + jg)
          = make_float4(t[m][0],t[m][1],t[m][2],t[m][3]);
      return;
    }
    __syncthreads();               // T visible to all
  }

  // ti != k here: out = (tj==k) ? -F@P : A[ti][tj] - F@T
  const float* S = needQ ? Q : P;
  float w[4][4] = {{0.f,0.f,0.f,0.f},{0.f,0.f,0.f,0.f},{0.f,0.f,0.f,0.f},{0.f,0.f,0.f,0.f}};
  for (int u4 = 0; u4 < 64; u4 += 4){
    float4 f0 = *(float4*)&F[(ib+0)*PAD + u4];
    float4 f1 = *(float4*)&F[(ib+1)*PAD + u4];
    float4 f2 = *(float4*)&F[(ib+2)*PAD + u4];
    float4 f3 = *(float4*)&F[(ib+3)*PAD + u4];
    float4 s0 = *(const float4*)&S[(u4+0)*PAD + jg];
    float4 s1 = *(const float4*)&S[(u4+1)*PAD + jg];
    float4 s2 = *(const float4*)&S[(u4+2)*PAD + jg];
    float4 s3 = *(const float4*)&S[(u4+3)*PAD + jg];
    ACC4(w[0], f0); ACC4(w[1], f1); ACC4(w[2], f2); ACC4(w[3], f3);
  }
  if (tj == k){
    #pragma unroll
    for (int m = 0; m < 4; ++m)
      *(float4*)(D + (size_t)(ti*64+ib+m)*TBINS + k*64 + jg)
        = make_float4(-w[m][0], -w[m][1], -w[m][2], -w[m][3]);
  } else {
    #pragma unroll
    for (int m = 0; m < 4; ++m){
      float4 av = *(const float4*)(A + (size_t)(ti*64+ib+m)*TBINS + tj*64 + jg);
      *(float4*)(D + (size_t)(ti*64+ib+m)*TBINS + tj*64 + jg)
        = make_float4(av.x - w[m][0], av.y - w[m][1], av.z - w[m][2], av.w - w[m][3]);
    }
  }
}

// ---------------- G_i = (sum_f Kinv_f) + lam_i I ----------------
__global__ void buildG_kernel(const float* __restrict__ A0, const double* __restrict__ lam,
                              float* __restrict__ A1){
  int idx = blockIdx.x*256 + threadIdx.x;       // 0..262143
  float s = 0.f;
  #pragma unroll
  for (int f2 = 0; f2 < NF; ++f2) s += A0[(size_t)f2*TBINS*TBINS + idx];
  bool diag = ((idx >> 9) == (idx & 511));
  #pragma unroll
  for (int i = 0; i < NF; ++i)
    A1[(size_t)i*TBINS*TBINS + idx] = s + (diag ? (float)lam[i] : 0.f);
}

// ---------------- term1 (V^T-rotated): bt[(t*8+i)*128+c] = sum_n crvV[i][n] spike[c][n][t] - cdV[i] ----------------
__global__ void term1_kernel(const float* __restrict__ spike, const float* __restrict__ crvVT,
                             const float* __restrict__ cdV, float* __restrict__ bt){
  __shared__ float crl[NNEU*NF];   // [n][i]
  __shared__ float ot[128][17];
  int t0 = blockIdx.x * 16;
  int c0 = blockIdx.y * 16;
  int tid = threadIdx.x;           // 256
  int tl = tid & 15, cl = tid >> 4;
  for (int n2 = tid; n2 < NNEU*NF; n2 += 256) crl[n2] = crvVT[n2];
  __syncthreads();
  float acc[8] = {0.f,0.f,0.f,0.f,0.f,0.f,0.f,0.f};
  const float* Sp = spike + (size_t)(c0+cl)*NNEU*TBINS + t0 + tl;
  for (int n = 0; n < NNEU; n += 4){
    float s0 = Sp[(size_t)(n+0)*TBINS];
    float s1 = Sp[(size_t)(n+1)*TBINS];
    float s2 = Sp[(size_t)(n+2)*TBINS];
    float s3 = Sp[(size_t)(n+3)*TBINS];
    #pragma unroll
    for (int i = 0; i < 8; ++i)
      acc[i] += crl[(n+0)*8+i]*s0 + crl[(n+1)*8+i]*s1 + crl[(n+2)*8+i]*s2 + crl[(n+3)*8+i]*s3;
  }
  #pragma unroll
  for (int i = 0; i < 8; ++i) ot[tl*8+i][cl] = acc[i] - cdV[i];
  __syncthreads();
  int row = tid >> 1, off = (tid & 1) * 8;    // row = tlocal*8+i
  int tt = t0 + (row >> 3), ii = row & 7;
  float* dst = bt + (size_t)(tt*8+ii)*NTRI + c0 + off;
  #pragma unroll
  for (int k = 0; k < 8; ++k) dst[k] = ot[row][off+k];
}

// ---------------- batched GEMM: xt_i = H_i (512x512) @ bt_i (512x128) ----------------
__global__ void gemm_kernel(const float* __restrict__ H, const float* __restrict__ bt,
                            float* __restrict__ xt){
  __shared__ float Ht[32][68];
  __shared__ float Bt[64][128];
  int i  = blockIdx.y;
  int t0 = blockIdx.x * 32;
  int tid = threadIdx.x;           // 256
  int gt = tid >> 5;               // 0..7
  int gc = tid & 31;               // 0..31
  float acc[4][4] = {{0.f,0.f,0.f,0.f},{0.f,0.f,0.f,0.f},{0.f,0.f,0.f,0.f},{0.f,0.f,0.f,0.f}};
  const float* Hi = H + (size_t)i*TBINS*TBINS;
  for (int uc = 0; uc < 8; ++uc){
    int u0 = uc*64;
    __syncthreads();
    for (int v = tid; v < 512; v += 256){
      int r = v >> 4, c4 = (v & 15) << 2;
      *(float4*)&Ht[r][c4] = *(const float4*)(Hi + (size_t)(t0+r)*TBINS + u0 + c4);
    }
    for (int v = tid; v < 2048; v += 256){
      int r = v >> 5, c4 = (v & 31) << 2;
      *(float4*)&Bt[r][c4] = *(const float4*)(bt + (size_t)((u0+r)*8 + i)*NTRI + c4);
    }
    __syncthreads();
    for (int u = 0; u < 64; ++u){
      float h0 = Ht[gt*4+0][u], h1 = Ht[gt*4+1][u], h2 = Ht[gt*4+2][u], h3 = Ht[gt*4+3][u];
      float b0 = Bt[u][gc], b1 = Bt[u][gc+32], b2 = Bt[u][gc+64], b3 = Bt[u][gc+96];
      acc[0][0] += h0*b0; acc[0][1] += h0*b1; acc[0][2] += h0*b2; acc[0][3] += h0*b3;
      acc[1][0] += h1*b0; acc[1][1] += h1*b1; acc[1][2] += h1*b2; acc[1][3] += h1*b3;
      acc[2][0] += h2*b0; acc[2][1] += h2*b1; acc[2][2] += h2*b2; acc[2][3] += h2*b3;
      acc[3][0] += h3*b0; acc[3][1] += h3*b1; acc[3][2] += h3*b2; acc[3][3] += h3*b3;
    }
  }
  #pragma unroll
  for (int m = 0; m < 4; ++m)
    #pragma unroll
    for (int j = 0; j < 4; ++j)
      xt[(size_t)((t0 + gt*4 + m)*8 + i)*NTRI + gc + 32*j] = acc[m][j];
}

// ---------------- output: out[c][f][t] = sum_i V[f][i] xt[(t*8+i)*128+c] ----------------
__global__ void output_kernel(const float* __restrict__ xt, const float* __restrict__ Vf,
                              float* __restrict__ out){
  __shared__ float T[128][68];
  __shared__ float Vl[64];
  int t0 = blockIdx.x * 64, c0 = blockIdx.y * 16;
  int tid = threadIdx.x;   // 256
  if (tid < 64) Vl[tid] = Vf[tid];
  __syncthreads();
  for (int idx = tid; idx < 1024; idx += 256){
    int tl = idx >> 4, cl = idx & 15;
    float xv[8];
    #pragma unroll
    for (int i = 0; i < 8; ++i)
      xv[i] = xt[(size_t)((t0+tl)*8+i)*NTRI + c0 + cl];
    #pragma unroll
    for (int f = 0; f < 8; ++f){
      float s = 0.f;
      #pragma unroll
      for (int i = 0; i < 8; ++i) s += Vl[f*8+i] * xv[i];
      T[cl*8+f][tl] = s;
    }
  }
  __syncthreads();
  int row = tid >> 1, half = tid & 1;   // row = cl*8+f
  int cc = c0 + (row >> 3), ff = row & 7;
  float* dst = out + (size_t)cc*NF*TBINS + ff*TBINS + t0 + half*32;
  #pragma unroll
  for (int k = 0; k < 8; ++k)
    ((float4*)dst)[k] = *(float4*)&T[row][half*32 + k*4];
}

extern "C" void kernel_launch(void* const* d_in, const int* in_sizes, int n_in,
                              void* d_out, int out_size, void* d_ws, size_t ws_size,
                              hipStream_t stream) {
  const float* spike  = (const float*)d_in[0];
  const float* Cm     = (const float*)d_in[1];
  const float* dm     = (const float*)d_in[2];
  const float* r_diag = (const float*)d_in[3];
  const float* gamma  = (const float*)d_in[4];
  float* out = (float*)d_out;
  float* ws = (float*)d_ws;

  float*  A0    = ws + OFF_A0;
  float*  A1    = ws + OFF_A1;
  float*  crvT  = ws + OFF_CRVT;
  float*  crvVT = ws + OFF_CRVVT;
  float*  ccT   = ws + OFF_CCT;
  float*  cd    = ws + OFF_CD;
  float*  cdV   = ws + OFF_CDV;
  float*  rinv  = ws + OFF_RINV;
  double* lam   = (double*)(ws + OFF_LAM);
  float*  Vf    = ws + OFF_VF;
  float*  bt    = ws + OFF_BT;
  float*  xt    = ws + OFF_XT;

  prep_kernel<<<1, 512, 0, stream>>>(Cm, dm, r_diag, crvT, ccT, cd, rinv);
  eig8_kernel<<<1, 64, 0, stream>>>(ccT, Vf, lam);
  rotv_kernel<<<1, 512, 0, stream>>>(crvT, cd, Vf, crvVT, cdV);
  buildK_kernel<<<dim3(1024, 8), 256, 0, stream>>>(gamma, A0);

  // chain 1: invert K_f (ping-pong A0 <-> A1, 8 steps -> result in A0)
  {
    float* s = A0; float* d = A1;
    for (int k = 0; k < 8; ++k){
      gj_step<<<dim3(64, 8), 256, 0, stream>>>(s, d, k);
      float* tmp = s; s = d; d = tmp;
    }
  }
  buildG_kernel<<<1024, 256, 0, stream>>>(A0, lam, A1);
  // chain 2: invert G_i (start A1, 8 steps -> H in A1)
  {
    float* s = A1; float* d = A0;
    for (int k = 0; k < 8; ++k){
      gj_step<<<dim3(64, 8), 256, 0, stream>>>(s, d, k);
      float* tmp = s; s = d; d = tmp;
    }
  }
  term1_kernel<<<dim3(32, 8), 256, 0, stream>>>(spike, crvVT, cdV, bt);
  gemm_kernel<<<dim3(16, 8), 256, 0, stream>>>(A1, bt, xt);
  output_kernel<<<dim3(8, 8), 256, 0, stream>>>(xt, Vf, out);
}

// Round 6
// 2582.551 us; speedup vs baseline: 6.6122x; 1.1991x over previous
//
#include <hip/hip_runtime.h>

// GPFA e-step posterior mean on MI355X — direct Kronecker-sum solve, fp32 chains.
// M = Kbar (x) I_F + I_T (x) A,  Kbar = sum_f inv(K_f),  A = C'R^-1 C = V Lam V'.
// Per factor-eigenpair i: (Kbar + lam_i I) xt_i = bt_i  (512x512, 128 RHS).
// GJ chains: one apply-kernel per step (pure tile GEMMs, pivot inverse read from
// global); the NEXT step's 64x64 pivot inversion is fused into the single
// designated block that produces tile (k+1,k+1). fp32 eig8 (hardware rcp/rsqrt).

#define NF 8
#define TBINS 512
#define NNEU 512
#define NTRI 128
#define PAD 68

// ---- ws layout (float offsets) ----
#define OFF_A0     0                 // float[8*512*512] ping
#define OFF_A1     2097152           // float[8*512*512] pong
#define OFF_CRVT   4194304           // float[512*8]
#define OFF_CRVVT  4198400           // float[512*8]
#define OFF_CCT    4202496           // float[64]
#define OFF_CD     4202560           // float[64]
#define OFF_CDV    4202624           // float[64]
#define OFF_RINV   4202688           // float[512]
#define OFF_LAM    4203200           // float[8]
#define OFF_VF     4203216           // float[64]
#define OFF_BT     4203280           // float[4096*128]
#define OFF_XT     4727568           // float[4096*128]
#define OFF_PP0    5251856           // float[8*4096] pivot-inverse buf A
#define OFF_PP1    5284624           // float[8*4096] pivot-inverse buf B

__device__ __forceinline__ void load8(float* v, const float* ptr){
  float4 a = ((const float4*)ptr)[0];
  float4 b = ((const float4*)ptr)[1];
  v[0]=a.x; v[1]=a.y; v[2]=a.z; v[3]=a.w;
  v[4]=b.x; v[5]=b.y; v[6]=b.z; v[7]=b.w;
}
__device__ __forceinline__ void store8(float* ptr, const float* v){
  ((float4*)ptr)[0] = make_float4(v[0],v[1],v[2],v[3]);
  ((float4*)ptr)[1] = make_float4(v[4],v[5],v[6],v[7]);
}

// in-place GJ inversion of 64x64 LDS tile P (SPD, no pivoting); 256 threads
__device__ __forceinline__ void gj_invert64(float* P, float* colk, float* rowk, int tid){
  int j = tid & 63, ig = tid >> 6;
  for (int kk = 0; kk < 64; ++kk){
    if (tid < 64) colk[tid] = P[tid*PAD + kk];
    else if (tid < 128) rowk[tid-64] = P[kk*PAD + (tid-64)];
    __syncthreads();
    float pinv = 1.0f / colk[kk];
    if (j == kk){
      #pragma unroll
      for (int m = 0; m < 16; ++m){
        int i = ig*16 + m;
        P[i*PAD + kk] = (i == kk) ? pinv : (-colk[i] * pinv);
      }
    } else {
      float newr = rowk[j] * pinv;
      #pragma unroll
      for (int m = 0; m < 16; ++m){
        int i = ig*16 + m;
        if (i == kk) P[kk*PAD + j] = newr;
        else P[i*PAD + j] -= colk[i] * newr;
      }
    }
    __syncthreads();
  }
}

// ---------------- prep ----------------
__global__ void prep_kernel(const float* __restrict__ Cm, const float* __restrict__ dm,
                            const float* __restrict__ r_diag,
                            float* __restrict__ crvT, float* __restrict__ ccT,
                            float* __restrict__ cd, float* __restrict__ rinv){
  __shared__ float s_crv[NNEU*NF];
  __shared__ float s_cm[NNEU*NF];
  __shared__ float s_dm[NNEU];
  int tid = threadIdx.x;            // 512; thread == neuron n
  float ri = 1.0f / r_diag[tid];
  rinv[tid] = ri;
  s_dm[tid] = dm[tid];
  #pragma unroll
  for (int f = 0; f < NF; ++f){
    float cv = Cm[tid*NF + f];
    s_cm[tid*NF + f] = cv;
    float v = cv * ri;
    s_crv[tid*NF + f] = v;
    crvT[tid*NF + f] = v;
  }
  __syncthreads();
  if (tid < 64){
    int f = tid >> 3, g = tid & 7;
    float acc = 0.f;
    for (int n = 0; n < NNEU; ++n) acc += s_crv[n*NF+f] * s_cm[n*NF+g];
    ccT[tid] = acc;
  } else if (tid < 72){
    int f = tid - 64;
    float acc = 0.f;
    for (int n = 0; n < NNEU; ++n) acc += s_crv[n*NF+f] * s_dm[n];
    cd[f] = acc;
  }
}

// ---------------- 8x8 eig: cyclic Jacobi, fp32, algebraic rotations ----------------
__global__ void eig8_kernel(const float* __restrict__ ccT,
                            float* __restrict__ Vf, float* __restrict__ lam){
  if (threadIdx.x != 0) return;
  float A[8][8], V[8][8];
  #pragma unroll
  for (int a = 0; a < 8; ++a)
    #pragma unroll
    for (int b = 0; b < 8; ++b){
      A[a][b] = ccT[a*8+b];
      V[a][b] = (a == b) ? 1.0f : 0.0f;
    }
  for (int sw = 0; sw < 8; ++sw){
    for (int p = 0; p < 7; ++p){
      for (int q = p+1; q < 8; ++q){
        float apq = A[p][q];
        if (fabsf(apq) < 1e-20f) continue;
        float beta = (A[q][q] - A[p][p]) / (2.0f * apq);
        float tt = ((beta >= 0.0f) ? 1.0f : -1.0f) / (fabsf(beta) + sqrtf(1.0f + beta*beta));
        float c = 1.0f / sqrtf(1.0f + tt*tt);
        float s = tt * c;
        #pragma unroll
        for (int kk = 0; kk < 8; ++kk){
          float akp = A[kk][p], akq = A[kk][q];
          A[kk][p] = c*akp - s*akq;
          A[kk][q] = s*akp + c*akq;
        }
        #pragma unroll
        for (int kk = 0; kk < 8; ++kk){
          float apk = A[p][kk], aqk = A[q][kk];
          A[p][kk] = c*apk - s*aqk;
          A[q][kk] = s*apk + c*aqk;
        }
        #pragma unroll
        for (int kk = 0; kk < 8; ++kk){
          float vkp = V[kk][p], vkq = V[kk][q];
          V[kk][p] = c*vkp - s*vkq;
          V[kk][q] = s*vkp + c*vkq;
        }
      }
    }
  }
  #pragma unroll
  for (int i = 0; i < 8; ++i) lam[i] = A[i][i];
  #pragma unroll
  for (int a = 0; a < 8; ++a)
    #pragma unroll
    for (int b = 0; b < 8; ++b) Vf[a*8+b] = V[a][b];
}

// ---------------- rotate crv, cd by V^T ----------------
__global__ void rotv_kernel(const float* __restrict__ crvT, const float* __restrict__ cd,
                            const float* __restrict__ Vf,
                            float* __restrict__ crvVT, float* __restrict__ cdV){
  __shared__ float Vl[64];
  int tid = threadIdx.x;   // 512
  if (tid < 64) Vl[tid] = Vf[tid];
  __syncthreads();
  float cv[8], ov[8];
  load8(cv, crvT + tid*8);
  #pragma unroll
  for (int i = 0; i < 8; ++i){
    float s = 0.f;
    #pragma unroll
    for (int f = 0; f < 8; ++f) s += Vl[f*8+i] * cv[f];
    ov[i] = s;
  }
  store8(crvVT + tid*8, ov);
  if (tid < 8){
    float s = 0.f;
    #pragma unroll
    for (int f = 0; f < 8; ++f) s += Vl[f*8+tid] * cd[f];
    cdV[tid] = s;
  }
}

// ---------------- build K_f (fp32) ----------------
__global__ void buildK_kernel(const float* __restrict__ gamma, float* __restrict__ A0){
  int f = blockIdx.y;
  int idx = blockIdx.x*256 + threadIdx.x;   // t*512+u
  int t = idx >> 9, u = idx & 511;
  float g = gamma[f];
  float d = (float)(t - u);
  float v = 0.999f * expf(-0.5f * g * d * d);
  if (t == u) v += 1.0e-3f;
  A0[(size_t)f*TBINS*TBINS + idx] = v;
}

// ---------------- G_i = (sum_f Kinv_f) + lam_i I ----------------
__global__ void buildG_kernel(const float* __restrict__ A0, const float* __restrict__ lam,
                              float* __restrict__ A1){
  int idx = blockIdx.x*256 + threadIdx.x;       // 0..262143
  float s = 0.f;
  #pragma unroll
  for (int f2 = 0; f2 < NF; ++f2) s += A0[(size_t)f2*TBINS*TBINS + idx];
  bool diag = ((idx >> 9) == (idx & 511));
  #pragma unroll
  for (int i = 0; i < NF; ++i)
    A1[(size_t)i*TBINS*TBINS + idx] = s + (diag ? lam[i] : 0.f);
}

// ---------------- standalone pivot inversion (chain head): Pout = inv(A[f][0:64][0:64]) ----------------
__global__ __launch_bounds__(256) void gj_pivot0(const float* __restrict__ A,
                                                 float* __restrict__ Pout){
  __shared__ float P[64*PAD];
  __shared__ float colk[64];
  __shared__ float rowk[64];
  int f = blockIdx.x;
  int tid = threadIdx.x;
  const float* Af = A + (size_t)f*TBINS*TBINS;
  for (int v = tid; v < 1024; v += 256){
    int r = v >> 4, c4 = (v & 15) << 2;
    *(float4*)&P[r*PAD + c4] = *(const float4*)(Af + (size_t)r*TBINS + c4);
  }
  __syncthreads();
  gj_invert64(P, colk, rowk, tid);
  for (int v = tid; v < 1024; v += 256){
    int r = v >> 4, c4 = (v & 15) << 2;
    *(float4*)(Pout + f*4096 + r*64 + c4) = *(float4*)&P[r*PAD + c4];
  }
}

// ---------------- GJ apply step: src -> dst; pivot inverse from Pin; designated
// block (k+1,k+1) also inverts its output tile -> Pout ----------------
#define ACC4(tm, fm) \
  tm[0] += fm.x*s0.x + fm.y*s1.x + fm.z*s2.x + fm.w*s3.x; \
  tm[1] += fm.x*s0.y + fm.y*s1.y + fm.z*s2.y + fm.w*s3.y; \
  tm[2] += fm.x*s0.z + fm.y*s1.z + fm.z*s2.z + fm.w*s3.z; \
  tm[3] += fm.x*s0.w + fm.y*s1.w + fm.z*s2.w + fm.w*s3.w;

__global__ __launch_bounds__(256) void gj_apply(const float* __restrict__ src,
                                                float* __restrict__ dst,
                                                const float* __restrict__ Pin,
                                                float* __restrict__ Pout,
                                                int k, int inv_next){
  __shared__ float P[64*PAD];
  __shared__ float Q[64*PAD];
  __shared__ float F[64*PAD];
  __shared__ float colk[64];
  __shared__ float rowk[64];
  int f  = blockIdx.y;
  int ti = blockIdx.x >> 3, tj = blockIdx.x & 7;
  int tid = threadIdx.x;
  const float* A = src + (size_t)f*TBINS*TBINS;
  float* D = dst + (size_t)f*TBINS*TBINS;

  // load pivot inverse (precomputed)
  for (int v = tid; v < 1024; v += 256){
    int r = v >> 4, c4 = (v & 15) << 2;
    *(float4*)&P[r*PAD + c4] = *(const float4*)(Pin + f*4096 + r*64 + c4);
  }
  if (tj != k){
    for (int v = tid; v < 1024; v += 256){
      int r = v >> 4, c4 = (v & 15) << 2;
      *(float4*)&Q[r*PAD + c4] = *(const float4*)(A + (size_t)(k*64+r)*TBINS + tj*64 + c4);
    }
  }
  if (ti != k){
    for (int v = tid; v < 1024; v += 256){
      int r = v >> 4, c4 = (v & 15) << 2;
      *(float4*)&F[r*PAD + c4] = *(const float4*)(A + (size_t)(ti*64+r)*TBINS + k*64 + c4);
    }
  }
  __syncthreads();

  int jg = (tid & 15) << 2;   // output cols jg..jg+3
  int ib = (tid >> 4) << 2;   // output rows ib..ib+3

  if (tj == k){
    if (ti == k){
      // pass-through: D[k][k] = P
      for (int v = tid; v < 1024; v += 256){
        int r = v >> 4, c4 = (v & 15) << 2;
        *(float4*)(D + (size_t)(k*64+r)*TBINS + k*64 + c4) = *(float4*)&P[r*PAD + c4];
      }
      return;
    }
    // D = -F @ P
    float w[4][4] = {{0.f,0.f,0.f,0.f},{0.f,0.f,0.f,0.f},{0.f,0.f,0.f,0.f},{0.f,0.f,0.f,0.f}};
    for (int u4 = 0; u4 < 64; u4 += 4){
      float4 f0 = *(float4*)&F[(ib+0)*PAD + u4];
      float4 f1 = *(float4*)&F[(ib+1)*PAD + u4];
      float4 f2 = *(float4*)&F[(ib+2)*PAD + u4];
      float4 f3 = *(float4*)&F[(ib+3)*PAD + u4];
      float4 s0 = *(float4*)&P[(u4+0)*PAD + jg];
      float4 s1 = *(float4*)&P[(u4+1)*PAD + jg];
      float4 s2 = *(float4*)&P[(u4+2)*PAD + jg];
      float4 s3 = *(float4*)&P[(u4+3)*PAD + jg];
      ACC4(w[0], f0); ACC4(w[1], f1); ACC4(w[2], f2); ACC4(w[3], f3);
    }
    #pragma unroll
    for (int m = 0; m < 4; ++m)
      *(float4*)(D + (size_t)(ti*64+ib+m)*TBINS + k*64 + jg)
        = make_float4(-w[m][0], -w[m][1], -w[m][2], -w[m][3]);
    return;
  }

  // tj != k: T = P @ Q (P symmetric: P'[ib][u] = P[u][ib])
  float t[4][4] = {{0.f,0.f,0.f,0.f},{0.f,0.f,0.f,0.f},{0.f,0.f,0.f,0.f},{0.f,0.f,0.f,0.f}};
  for (int u = 0; u < 64; ++u){
    float4 pv = *(float4*)&P[u*PAD + ib];
    float4 qv = *(float4*)&Q[u*PAD + jg];
    t[0][0]+=pv.x*qv.x; t[0][1]+=pv.x*qv.y; t[0][2]+=pv.x*qv.z; t[0][3]+=pv.x*qv.w;
    t[1][0]+=pv.y*qv.x; t[1][1]+=pv.y*qv.y; t[1][2]+=pv.y*qv.z; t[1][3]+=pv.y*qv.w;
    t[2][0]+=pv.z*qv.x; t[2][1]+=pv.z*qv.y; t[2][2]+=pv.z*qv.z; t[2][3]+=pv.z*qv.w;
    t[3][0]+=pv.w*qv.x; t[3][1]+=pv.w*qv.y; t[3][2]+=pv.w*qv.z; t[3][3]+=pv.w*qv.w;
  }
  if (ti == k){
    // D = T directly from registers
    #pragma unroll
    for (int m = 0; m < 4; ++m)
      *(float4*)(D + (size_t)(k*64+ib+m)*TBINS + tj*64 + jg)
        = make_float4(t[m][0],t[m][1],t[m][2],t[m][3]);
    return;
  }
  __syncthreads();               // all reads of Q done
  #pragma unroll
  for (int m = 0; m < 4; ++m)
    *(float4*)&Q[(ib+m)*PAD + jg] = make_float4(t[m][0],t[m][1],t[m][2],t[m][3]);
  __syncthreads();               // T visible to all

  // Schur: D = A[ti][tj] - F @ T
  float w[4][4] = {{0.f,0.f,0.f,0.f},{0.f,0.f,0.f,0.f},{0.f,0.f,0.f,0.f},{0.f,0.f,0.f,0.f}};
  for (int u4 = 0; u4 < 64; u4 += 4){
    float4 f0 = *(float4*)&F[(ib+0)*PAD + u4];
    float4 f1 = *(float4*)&F[(ib+1)*PAD + u4];
    float4 f2 = *(float4*)&F[(ib+2)*PAD + u4];
    float4 f3 = *(float4*)&F[(ib+3)*PAD + u4];
    float4 s0 = *(float4*)&Q[(u4+0)*PAD + jg];
    float4 s1 = *(float4*)&Q[(u4+1)*PAD + jg];
    float4 s2 = *(float4*)&Q[(u4+2)*PAD + jg];
    float4 s3 = *(float4*)&Q[(u4+3)*PAD + jg];
    ACC4(w[0], f0); ACC4(w[1], f1); ACC4(w[2], f2); ACC4(w[3], f3);
  }
  #pragma unroll
  for (int m = 0; m < 4; ++m){
    float4 av = *(const float4*)(A + (size_t)(ti*64+ib+m)*TBINS + tj*64 + jg);
    float4 dv = make_float4(av.x - w[m][0], av.y - w[m][1], av.z - w[m][2], av.w - w[m][3]);
    *(float4*)(D + (size_t)(ti*64+ib+m)*TBINS + tj*64 + jg) = dv;
    w[m][0] = dv.x; w[m][1] = dv.y; w[m][2] = dv.z; w[m][3] = dv.w;
  }

  // designated block also inverts its tile -> next step's pivot inverse
  if (inv_next && ti == k+1 && tj == k+1){
    __syncthreads();
    #pragma unroll
    for (int m = 0; m < 4; ++m)
      *(float4*)&P[(ib+m)*PAD + jg] = make_float4(w[m][0],w[m][1],w[m][2],w[m][3]);
    __syncthreads();
    gj_invert64(P, colk, rowk, tid);
    for (int v = tid; v < 1024; v += 256){
      int r = v >> 4, c4 = (v & 15) << 2;
      *(float4*)(Pout + f*4096 + r*64 + c4) = *(float4*)&P[r*PAD + c4];
    }
  }
}

// ---------------- term1: bt[(t*8+i)*128+c] = sum_n crvV[i][n] spike[c][n][t] - cdV[i] ----------------
__global__ void term1_kernel(const float* __restrict__ spike, const float* __restrict__ crvVT,
                             const float* __restrict__ cdV, float* __restrict__ bt){
  __shared__ float crl[NNEU*NF];   // [n][i]
  __shared__ float ot[128][17];
  int t0 = blockIdx.x * 16;
  int c0 = blockIdx.y * 16;
  int tid = threadIdx.x;           // 256
  int tl = tid & 15, cl = tid >> 4;
  for (int n2 = tid; n2 < NNEU*NF; n2 += 256) crl[n2] = crvVT[n2];
  __syncthreads();
  float acc[8] = {0.f,0.f,0.f,0.f,0.f,0.f,0.f,0.f};
  const float* Sp = spike + (size_t)(c0+cl)*NNEU*TBINS + t0 + tl;
  for (int n = 0; n < NNEU; n += 4){
    float s0 = Sp[(size_t)(n+0)*TBINS];
    float s1 = Sp[(size_t)(n+1)*TBINS];
    float s2 = Sp[(size_t)(n+2)*TBINS];
    float s3 = Sp[(size_t)(n+3)*TBINS];
    #pragma unroll
    for (int i = 0; i < 8; ++i)
      acc[i] += crl[(n+0)*8+i]*s0 + crl[(n+1)*8+i]*s1 + crl[(n+2)*8+i]*s2 + crl[(n+3)*8+i]*s3;
  }
  #pragma unroll
  for (int i = 0; i < 8; ++i) ot[tl*8+i][cl] = acc[i] - cdV[i];
  __syncthreads();
  int row = tid >> 1, off = (tid & 1) * 8;    // row = tlocal*8+i
  int tt = t0 + (row >> 3), ii = row & 7;
  float* dst = bt + (size_t)(tt*8+ii)*NTRI + c0 + off;
  #pragma unroll
  for (int k = 0; k < 8; ++k) dst[k] = ot[row][off+k];
}

// ---------------- batched GEMM: xt_i = H_i (512x512) @ bt_i (512x128) ----------------
__global__ void gemm_kernel(const float* __restrict__ H, const float* __restrict__ bt,
                            float* __restrict__ xt){
  __shared__ float Ht[32][68];
  __shared__ float Bt[64][128];
  int i  = blockIdx.y;
  int t0 = blockIdx.x * 32;
  int tid = threadIdx.x;           // 256
  int gt = tid >> 5;               // 0..7
  int gc = tid & 31;               // 0..31
  float acc[4][4] = {{0.f,0.f,0.f,0.f},{0.f,0.f,0.f,0.f},{0.f,0.f,0.f,0.f},{0.f,0.f,0.f,0.f}};
  const float* Hi = H + (size_t)i*TBINS*TBINS;
  for (int uc = 0; uc < 8; ++uc){
    int u0 = uc*64;
    __syncthreads();
    for (int v = tid; v < 512; v += 256){
      int r = v >> 4, c4 = (v & 15) << 2;
      *(float4*)&Ht[r][c4] = *(const float4*)(Hi + (size_t)(t0+r)*TBINS + u0 + c4);
    }
    for (int v = tid; v < 2048; v += 256){
      int r = v >> 5, c4 = (v & 31) << 2;
      *(float4*)&Bt[r][c4] = *(const float4*)(bt + (size_t)((u0+r)*8 + i)*NTRI + c4);
    }
    __syncthreads();
    for (int u = 0; u < 64; ++u){
      float h0 = Ht[gt*4+0][u], h1 = Ht[gt*4+1][u], h2 = Ht[gt*4+2][u], h3 = Ht[gt*4+3][u];
      float b0 = Bt[u][gc], b1 = Bt[u][gc+32], b2 = Bt[u][gc+64], b3 = Bt[u][gc+96];
      acc[0][0] += h0*b0; acc[0][1] += h0*b1; acc[0][2] += h0*b2; acc[0][3] += h0*b3;
      acc[1][0] += h1*b0; acc[1][1] += h1*b1; acc[1][2] += h1*b2; acc[1][3] += h1*b3;
      acc[2][0] += h2*b0; acc[2][1] += h2*b1; acc[2][2] += h2*b2; acc[2][3] += h2*b3;
      acc[3][0] += h3*b0; acc[3][1] += h3*b1; acc[3][2] += h3*b2; acc[3][3] += h3*b3;
    }
  }
  #pragma unroll
  for (int m = 0; m < 4; ++m)
    #pragma unroll
    for (int j = 0; j < 4; ++j)
      xt[(size_t)((t0 + gt*4 + m)*8 + i)*NTRI + gc + 32*j] = acc[m][j];
}

// ---------------- output: out[c][f][t] = sum_i V[f][i] xt[(t*8+i)*128+c] ----------------
__global__ void output_kernel(const float* __restrict__ xt, const float* __restrict__ Vf,
                              float* __restrict__ out){
  __shared__ float T[128][68];
  __shared__ float Vl[64];
  int t0 = blockIdx.x * 64, c0 = blockIdx.y * 16;
  int tid = threadIdx.x;   // 256
  if (tid < 64) Vl[tid] = Vf[tid];
  __syncthreads();
  for (int idx = tid; idx < 1024; idx += 256){
    int tl = idx >> 4, cl = idx & 15;
    float xv[8];
    #pragma unroll
    for (int i = 0; i < 8; ++i)
      xv[i] = xt[(size_t)((t0+tl)*8+i)*NTRI + c0 + cl];
    #pragma unroll
    for (int f = 0; f < 8; ++f){
      float s = 0.f;
      #pragma unroll
      for (int i = 0; i < 8; ++i) s += Vl[f*8+i] * xv[i];
      T[cl*8+f][tl] = s;
    }
  }
  __syncthreads();
  int row = tid >> 1, half = tid & 1;   // row = cl*8+f
  int cc = c0 + (row >> 3), ff = row & 7;
  float* dst = out + (size_t)cc*NF*TBINS + ff*TBINS + t0 + half*32;
  #pragma unroll
  for (int k = 0; k < 8; ++k)
    ((float4*)dst)[k] = *(float4*)&T[row][half*32 + k*4];
}

extern "C" void kernel_launch(void* const* d_in, const int* in_sizes, int n_in,
                              void* d_out, int out_size, void* d_ws, size_t ws_size,
                              hipStream_t stream) {
  const float* spike  = (const float*)d_in[0];
  const float* Cm     = (const float*)d_in[1];
  const float* dm     = (const float*)d_in[2];
  const float* r_diag = (const float*)d_in[3];
  const float* gamma  = (const float*)d_in[4];
  float* out = (float*)d_out;
  float* ws = (float*)d_ws;

  float*  A0    = ws + OFF_A0;
  float*  A1    = ws + OFF_A1;
  float*  crvT  = ws + OFF_CRVT;
  float*  crvVT = ws + OFF_CRVVT;
  float*  ccT   = ws + OFF_CCT;
  float*  cd    = ws + OFF_CD;
  float*  cdV   = ws + OFF_CDV;
  float*  rinv  = ws + OFF_RINV;
  float*  lam   = ws + OFF_LAM;
  float*  Vf    = ws + OFF_VF;
  float*  bt    = ws + OFF_BT;
  float*  xt    = ws + OFF_XT;
  float*  Pb[2] = { ws + OFF_PP0, ws + OFF_PP1 };

  prep_kernel<<<1, 512, 0, stream>>>(Cm, dm, r_diag, crvT, ccT, cd, rinv);
  eig8_kernel<<<1, 64, 0, stream>>>(ccT, Vf, lam);
  rotv_kernel<<<1, 512, 0, stream>>>(crvT, cd, Vf, crvVT, cdV);
  buildK_kernel<<<dim3(1024, 8), 256, 0, stream>>>(gamma, A0);

  // chain 1: invert K_f (ping-pong A0 <-> A1, 8 steps -> result in A0)
  gj_pivot0<<<8, 256, 0, stream>>>(A0, Pb[0]);
  {
    float* s = A0; float* d = A1;
    for (int k = 0; k < 8; ++k){
      gj_apply<<<dim3(64, 8), 256, 0, stream>>>(s, d, Pb[k&1], Pb[(k+1)&1], k, (k < 7) ? 1 : 0);
      float* tmp = s; s = d; d = tmp;
    }
  }
  buildG_kernel<<<1024, 256, 0, stream>>>(A0, lam, A1);
  // chain 2: invert G_i (start A1, 8 steps -> H in A1)
  gj_pivot0<<<8, 256, 0, stream>>>(A1, Pb[0]);
  {
    float* s = A1; float* d = A0;
    for (int k = 0; k < 8; ++k){
      gj_apply<<<dim3(64, 8), 256, 0, stream>>>(s, d, Pb[k&1], Pb[(k+1)&1], k, (k < 7) ? 1 : 0);
      float* tmp = s; s = d; d = tmp;
    }
  }
  term1_kernel<<<dim3(32, 8), 256, 0, stream>>>(spike, crvVT, cdV, bt);
  gemm_kernel<<<dim3(16, 8), 256, 0, stream>>>(A1, bt, xt);
  output_kernel<<<dim3(8, 8), 256, 0, stream>>>(xt, Vf, out);
}